// Round 2
// baseline (15866.695 us; speedup 1.0000x reference)
//
#include <hip/hip_runtime.h>
#include <hip/hip_bf16.h>

typedef __hip_bfloat16 bf16;

// ---------------------------------------------------------------------------
//   x: (8,4096,80) -> conv1(1->128,s2) -> (8,128,2048,40)
//   -> conv2(128->256,s2) -> (8,256,1024,20)
//   -> conv3(256->512,s1) -> (8,512,1024,20)
//   -> embed GEMM (8192 x 512 x 10240) -> 4 RWKV blocks -> final LN
// Conv frontend runs in 4 chunks of 2 batches to keep workspace <= 132 MB.
// ---------------------------------------------------------------------------

constexpr int A_F32 = 0, A_EMBED = 1, A_MIX = 2, A_BF16 = 3;
constexpr int B_F32 = 0, B_CONV = 1;
constexpr int EP_CONV = 0, EP_BIAS_F32 = 1, EP_F32 = 2, EP_SIG = 3,
              EP_SQRELU_BF16 = 4, EP_ADD = 5, EP_ADDMUL = 6;

// ---------------------------------------------------------------------------
// Generic 64x64x16 f32 tiled GEMM. C[M,N] = A[M,K] * B[K,N] (+ epilogue).
// ---------------------------------------------------------------------------
template <int AL, int BL, int EPM, int TIN, int FIN, int STRIDE, int ICN>
__global__ __launch_bounds__(256) void gemm_k(
    const float* __restrict__ Af, const bf16* __restrict__ Abf,
    const float* __restrict__ amix,
    const float* __restrict__ Bf, const bf16* __restrict__ Bbf,
    float* __restrict__ C, bf16* __restrict__ Cb,
    const float* __restrict__ bias, const float* __restrict__ mul,
    int M, int N, int K)
{
    __shared__ float As[16][68];
    __shared__ float Bs[16][68];
    const int tid = threadIdx.x;
    const int n0 = blockIdx.x * 64;
    const int m0 = blockIdx.y * 64;
    const int tx = tid & 15, ty = tid >> 4;
    float acc[4][4] = {};

    for (int k0 = 0; k0 < K; k0 += 16) {
        // ---- A tile: 64(m) x 16(k)
#pragma unroll
        for (int i = 0; i < 4; i++) {
            int l = i * 256 + tid;
            int ml = l >> 4, kl = l & 15;
            int m = m0 + ml, k = k0 + kl;
            float v;
            if constexpr (AL == A_F32) {
                v = Af[(size_t)m * K + k];
            } else if constexpr (AL == A_BF16) {
                v = __bfloat162float(Abf[(size_t)m * K + k]);
            } else if constexpr (AL == A_MIX) {
                // token-shift mix fused: u = m % 1024 within each batch row
                int u = m & 1023;
                float cur = Af[(size_t)m * K + k];
                float sh = u ? Af[(size_t)(m - 1) * K + k] : 0.f;
                float a = amix[k];
                v = cur * a + sh * (1.f - a);
            } else {  // A_EMBED: gather from conv3 chunk out (b2,c,u,fo) bf16
                int b = m >> 10, u = m & 1023;
                int c = k / 20, fo = k - c * 20;
                v = __bfloat162float(Abf[(size_t)b * 10485760 + c * 20480 + u * 20 + fo]);
            }
            As[kl][ml] = v;
        }
        // ---- B tile: 16(k) x 64(n)
#pragma unroll
        for (int i = 0; i < 4; i++) {
            int l = i * 256 + tid;
            int kl = l >> 6, nl = l & 63;
            int k = k0 + kl, n = n0 + nl;
            float v;
            if constexpr (BL == B_F32) {
                v = Bf[(size_t)k * N + n];
            } else {  // B_CONV: im2col gather from bf16 (b2, ic, TIN, FIN)
                int b = n / 20480;
                int s = n - b * 20480;
                int to = s / 20, fo = s - to * 20;
                int ic = k / 9;
                int r = k - ic * 9;
                int kt = r / 3, kf = r - kt * 3;
                int ti = to * STRIDE - 1 + kt;
                int fi = fo * STRIDE - 1 + kf;
                v = 0.f;
                if ((unsigned)ti < (unsigned)TIN && (unsigned)fi < (unsigned)FIN)
                    v = __bfloat162float(
                        Bbf[(size_t)b * ((size_t)ICN * TIN * FIN) + ((size_t)ic * TIN + ti) * FIN + fi]);
            }
            Bs[kl][nl] = v;
        }
        __syncthreads();
#pragma unroll
        for (int kk = 0; kk < 16; kk++) {
            float a[4], bb[4];
#pragma unroll
            for (int j = 0; j < 4; j++) a[j] = As[kk][ty * 4 + j];
#pragma unroll
            for (int j = 0; j < 4; j++) bb[j] = Bs[kk][tx * 4 + j];
#pragma unroll
            for (int i = 0; i < 4; i++)
#pragma unroll
                for (int j = 0; j < 4; j++) acc[i][j] += a[i] * bb[j];
        }
        __syncthreads();
    }

    // ---- epilogue
#pragma unroll
    for (int i = 0; i < 4; i++) {
        int row = m0 + ty * 4 + i;
#pragma unroll
        for (int j = 0; j < 4; j++) {
            int col = n0 + tx * 4 + j;
            float v = acc[i][j];
            if constexpr (EPM == EP_CONV) {
                v += bias[row];
                v = v > 0.f ? v : 0.f;
                int b = col / 20480;
                int s = col - b * 20480;
                Cb[(size_t)b * ((size_t)M * 20480) + (size_t)row * 20480 + s] = __float2bfloat16(v);
            } else if constexpr (EPM == EP_BIAS_F32) {
                C[(size_t)row * N + col] = v + bias[col];
            } else if constexpr (EPM == EP_F32) {
                C[(size_t)row * N + col] = v;
            } else if constexpr (EPM == EP_SIG) {
                C[(size_t)row * N + col] = 1.f / (1.f + __expf(-v));
            } else if constexpr (EPM == EP_SQRELU_BF16) {
                float t = v > 0.f ? v : 0.f;
                Cb[(size_t)row * N + col] = __float2bfloat16(t * t);
            } else if constexpr (EPM == EP_ADD) {
                C[(size_t)row * N + col] += v;
            } else if constexpr (EPM == EP_ADDMUL) {
                size_t idx = (size_t)row * N + col;
                C[idx] += mul[idx] * v;
            }
        }
    }
}

// ---------------------------------------------------------------------------
// conv1 for a 2-batch chunk: 1 input channel, direct.
// out bf16 (b2, oc, t, f): b*10485760 + oc*81920 + t*40 + f
// ---------------------------------------------------------------------------
__global__ __launch_bounds__(256) void conv1_k(
    const float* __restrict__ x, const float* __restrict__ w,
    const float* __restrict__ bias, bf16* __restrict__ out)
{
    __shared__ float ws_[128 * 9];
    __shared__ float bs_[128];
    const int tid = threadIdx.x;
    for (int i = tid; i < 128 * 9; i += 256) ws_[i] = w[i];
    if (tid < 128) bs_[tid] = bias[tid];
    __syncthreads();

    int idx = blockIdx.x * 256 + tid;  // 2*2048*40 = 163840 total
    int f = idx % 40;
    int t = (idx / 40) & 2047;
    int b = idx / 81920;  // 0..1

    float xin[9];
#pragma unroll
    for (int kt = 0; kt < 3; kt++)
#pragma unroll
        for (int kf = 0; kf < 3; kf++) {
            int ti = 2 * t - 1 + kt, fi = 2 * f - 1 + kf;
            float v = 0.f;
            if ((unsigned)ti < 4096u && (unsigned)fi < 80u)
                v = x[(size_t)b * 327680 + (size_t)ti * 80 + fi];
            xin[kt * 3 + kf] = v;
        }
    size_t obase = (size_t)b * 10485760 + (size_t)t * 40 + f;
    for (int oc = 0; oc < 128; oc++) {
        float a = bs_[oc];
#pragma unroll
        for (int q = 0; q < 9; q++) a += ws_[oc * 9 + q] * xin[q];
        a = a > 0.f ? a : 0.f;
        out[obase + (size_t)oc * 81920] = __float2bfloat16(a);
    }
}

// ---------------------------------------------------------------------------
// LayerNorm over D=512, one wave per row (4 rows / block)
// ---------------------------------------------------------------------------
__global__ __launch_bounds__(256) void ln_k(
    const float* __restrict__ in, float* __restrict__ out,
    const float* __restrict__ g, const float* __restrict__ b, int M)
{
    int wave = threadIdx.x >> 6;
    int lane = threadIdx.x & 63;
    int row = blockIdx.x * 4 + wave;
    if (row >= M) return;
    const float* p = in + (size_t)row * 512;
    float v[8], s = 0.f, sq = 0.f;
#pragma unroll
    for (int i = 0; i < 8; i++) {
        v[i] = p[lane + i * 64];
        s += v[i];
        sq += v[i] * v[i];
    }
#pragma unroll
    for (int o = 32; o > 0; o >>= 1) {
        s += __shfl_xor(s, o, 64);
        sq += __shfl_xor(sq, o, 64);
    }
    float mean = s * (1.f / 512.f);
    float var = sq * (1.f / 512.f) - mean * mean;
    float r = rsqrtf(var + 1e-5f);
    float* q = out + (size_t)row * 512;
#pragma unroll
    for (int i = 0; i < 8; i++) {
        int d = lane + i * 64;
        q[d] = (v[i] - mean) * r * g[d] + b[d];
    }
}

// ---------------------------------------------------------------------------
// WKV sequential scan; one thread per (b,d); out = r*wkv.
// NOTE: outbuf may alias rbuf (read-before-write per element) -> no restrict.
// ---------------------------------------------------------------------------
__global__ __launch_bounds__(256) void wkv_k(
    const float* __restrict__ kbuf, const float* __restrict__ vbuf,
    const float* rbuf, float* outbuf,
    const float* __restrict__ decay, const float* __restrict__ first)
{
    int idx = blockIdx.x * 256 + threadIdx.x;  // 8*512 = 4096
    int d = idx & 511;
    int b = idx >> 9;
    float w = -__expf(decay[d]);
    float u = first[d];
    float aa = 0.f, bb = 0.f, pp = -1e38f;
    size_t base = (size_t)b * 1024 * 512 + d;
    for (int t = 0; t < 1024; t++) {
        size_t o = base + (size_t)t * 512;
        float kt = kbuf[o], vt = vbuf[o];
        float rt = rbuf[o];
        float ww = u + kt;
        float p = pp > ww ? pp : ww;
        float e1 = __expf(pp - p), e2 = __expf(ww - p);
        float out = (e1 * aa + e2 * vt) / (e1 * bb + e2);
        outbuf[o] = rt * out;
        float ww2 = pp + w;
        float p2 = ww2 > kt ? ww2 : kt;
        e1 = __expf(ww2 - p2);
        e2 = __expf(kt - p2);
        aa = e1 * aa + e2 * vt;
        bb = e1 * bb + e2;
        pp = p2;
    }
}

__global__ void olens_k(const int* __restrict__ x_len, float* __restrict__ out)
{
    int i = threadIdx.x;
    if (i < 8) {
        int l1 = (x_len[i] - 1) / 2 + 1;
        int ol = (l1 - 1) / 2 + 1;
        out[i] = (float)ol;
    }
}

// ---------------------------------------------------------------------------
extern "C" void kernel_launch(void* const* d_in, const int* in_sizes, int n_in,
                              void* d_out, int out_size, void* d_ws, size_t ws_size,
                              hipStream_t stream)
{
    (void)in_sizes; (void)n_in; (void)out_size; (void)ws_size;
    const float* x         = (const float*)d_in[0];
    const int*   x_len     = (const int*)d_in[1];
    const float* conv1_w   = (const float*)d_in[2];
    const float* conv1_b   = (const float*)d_in[3];
    const float* conv2_w   = (const float*)d_in[4];
    const float* conv2_b   = (const float*)d_in[5];
    const float* conv3_w   = (const float*)d_in[6];
    const float* conv3_b   = (const float*)d_in[7];
    const float* embed_w   = (const float*)d_in[8];
    const float* embed_b   = (const float*)d_in[9];
    const float* embed_ln_g= (const float*)d_in[10];
    const float* embed_ln_b= (const float*)d_in[11];
    const float* ln_att_g  = (const float*)d_in[12];
    const float* ln_att_b  = (const float*)d_in[13];
    const float* att_decay = (const float*)d_in[14];
    const float* att_first = (const float*)d_in[15];
    const float* att_mix_k = (const float*)d_in[16];
    const float* att_mix_v = (const float*)d_in[17];
    const float* att_mix_r = (const float*)d_in[18];
    const float* att_wk    = (const float*)d_in[19];
    const float* att_wv    = (const float*)d_in[20];
    const float* att_wr    = (const float*)d_in[21];
    const float* att_wo    = (const float*)d_in[22];
    const float* ln_ffn_g  = (const float*)d_in[23];
    const float* ln_ffn_b  = (const float*)d_in[24];
    const float* ffn_mix_k = (const float*)d_in[25];
    const float* ffn_mix_r = (const float*)d_in[26];
    const float* ffn_wk    = (const float*)d_in[27];
    const float* ffn_wv    = (const float*)d_in[28];
    const float* ffn_wr    = (const float*)d_in[29];
    const float* final_ln_g= (const float*)d_in[30];
    const float* final_ln_b= (const float*)d_in[31];

    // ---- workspace layout (total 132 MB) ----
    // 0    ..16MB : h    (8192x512 f32)
    // 16MB ..32MB : xn   (8192x512 f32)
    // 32MB ..48MB : kb   (8192x512 f32)   | conv phase: c1b bf16 32..72MB
    // 48MB ..64MB : vb                    |             c2b bf16 72..92MB
    // 64MB ..80MB : rb                    |             c3b bf16 92..132MB
    // 80MB ..112MB: kkb  (8192x2048 bf16)
    char* wsb = (char*)d_ws;
    float* h   = (float*)(wsb);
    float* xn  = (float*)(wsb + (16LL << 20));
    float* kb  = (float*)(wsb + (32LL << 20));
    float* vb  = (float*)(wsb + (48LL << 20));
    float* rb  = (float*)(wsb + (64LL << 20));
    bf16*  kkb = (bf16*) (wsb + (80LL << 20));
    bf16*  c1b = (bf16*) (wsb + (32LL << 20));
    bf16*  c2b = (bf16*) (wsb + (72LL << 20));
    bf16*  c3b = (bf16*) (wsb + (92LL << 20));

    // ---- conv frontend + embed, 2 batches per chunk
    for (int chunk = 0; chunk < 4; chunk++) {
        int b0 = chunk * 2;
        conv1_k<<<640, 256, 0, stream>>>(x + (size_t)b0 * 327680, conv1_w, conv1_b, c1b);
        gemm_k<A_F32, B_CONV, EP_CONV, 2048, 40, 2, 128><<<dim3(640, 4), 256, 0, stream>>>(
            conv2_w, nullptr, nullptr, nullptr, c1b, nullptr, c2b, conv2_b, nullptr,
            256, 40960, 1152);
        gemm_k<A_F32, B_CONV, EP_CONV, 1024, 20, 1, 256><<<dim3(640, 8), 256, 0, stream>>>(
            conv3_w, nullptr, nullptr, nullptr, c2b, nullptr, c3b, conv3_b, nullptr,
            512, 40960, 2304);
        gemm_k<A_EMBED, B_F32, EP_BIAS_F32, 0, 0, 0, 0><<<dim3(8, 32), 256, 0, stream>>>(
            nullptr, c3b, nullptr, embed_w, nullptr,
            xn + (size_t)b0 * 1024 * 512, nullptr, embed_b, nullptr,
            2048, 512, 10240);
    }
    ln_k<<<2048, 256, 0, stream>>>(xn, h, embed_ln_g, embed_ln_b, 8192);

    // ---- 4 RWKV blocks
    for (int i = 0; i < 4; i++) {
        // time mixing
        ln_k<<<2048, 256, 0, stream>>>(h, xn, ln_att_g + i * 512, ln_att_b + i * 512, 8192);
        gemm_k<A_MIX, B_F32, EP_F32, 0, 0, 0, 0><<<dim3(8, 128), 256, 0, stream>>>(
            xn, nullptr, att_mix_k + i * 512, att_wk + i * 262144, nullptr,
            kb, nullptr, nullptr, nullptr, 8192, 512, 512);
        gemm_k<A_MIX, B_F32, EP_F32, 0, 0, 0, 0><<<dim3(8, 128), 256, 0, stream>>>(
            xn, nullptr, att_mix_v + i * 512, att_wv + i * 262144, nullptr,
            vb, nullptr, nullptr, nullptr, 8192, 512, 512);
        gemm_k<A_MIX, B_F32, EP_SIG, 0, 0, 0, 0><<<dim3(8, 128), 256, 0, stream>>>(
            xn, nullptr, att_mix_r + i * 512, att_wr + i * 262144, nullptr,
            rb, nullptr, nullptr, nullptr, 8192, 512, 512);
        wkv_k<<<16, 256, 0, stream>>>(kb, vb, rb, rb, att_decay + i * 512, att_first + i * 512);
        gemm_k<A_F32, B_F32, EP_ADD, 0, 0, 0, 0><<<dim3(8, 128), 256, 0, stream>>>(
            rb, nullptr, nullptr, att_wo + i * 262144, nullptr,
            h, nullptr, nullptr, nullptr, 8192, 512, 512);
        // channel mixing
        ln_k<<<2048, 256, 0, stream>>>(h, xn, ln_ffn_g + i * 512, ln_ffn_b + i * 512, 8192);
        gemm_k<A_MIX, B_F32, EP_SQRELU_BF16, 0, 0, 0, 0><<<dim3(32, 128), 256, 0, stream>>>(
            xn, nullptr, ffn_mix_k + i * 512, ffn_wk + i * 1048576, nullptr,
            nullptr, kkb, nullptr, nullptr, 8192, 2048, 512);
        gemm_k<A_MIX, B_F32, EP_SIG, 0, 0, 0, 0><<<dim3(8, 128), 256, 0, stream>>>(
            xn, nullptr, ffn_mix_r + i * 512, ffn_wr + i * 262144, nullptr,
            rb, nullptr, nullptr, nullptr, 8192, 512, 512);
        gemm_k<A_BF16, B_F32, EP_ADDMUL, 0, 0, 0, 0><<<dim3(8, 128), 256, 0, stream>>>(
            nullptr, kkb, nullptr, ffn_wv + i * 1048576, nullptr,
            h, nullptr, nullptr, rb, 8192, 512, 2048);
    }

    // ---- final LN straight into d_out, then olens
    ln_k<<<2048, 256, 0, stream>>>(h, (float*)d_out, final_ln_g, final_ln_b, 8192);
    olens_k<<<1, 64, 0, stream>>>(x_len, (float*)d_out + 4194304);
}

// Round 3
// 8675.102 us; speedup vs baseline: 1.8290x; 1.8290x over previous
//
#include <hip/hip_runtime.h>
#include <hip/hip_bf16.h>

typedef __hip_bfloat16 bf16;
typedef __bf16 v8bf __attribute__((ext_vector_type(8)));
typedef float v4f __attribute__((ext_vector_type(4)));

// ---------------------------------------------------------------------------
//   x: (8,4096,80) -> conv1(1->128,s2) -> (8,128,2048,40)
//   -> conv2(128->256,s2) -> (8,256,1024,20)
//   -> conv3(256->512,s1) -> tokens (8,1024,10240) [token-major]
//   -> embed GEMM (8192 x 512 x 10240) -> 4 RWKV blocks -> final LN
// Conv frontend runs in 4 chunks of 2 batches to keep workspace <= 132 MB.
// GEMM core: bf16 MFMA 16x16x32, 128x128 tile, BK=32, 4 waves/block.
// ---------------------------------------------------------------------------

constexpr int A_F32 = 0, A_MIX = 1, A_BF16 = 2;
constexpr int B_F32 = 0, B_CONV = 1;
constexpr int EP_CONV = 0, EP_CONV_T = 1, EP_BIAS_F32 = 2, EP_F32 = 3,
              EP_SIG = 4, EP_SQRELU_BF16 = 5, EP_ADD = 6, EP_ADDMUL = 7;

static __device__ __forceinline__ unsigned short f2b(float f) {
    return __builtin_bit_cast(unsigned short, __float2bfloat16(f));
}

// ---------------------------------------------------------------------------
// MFMA GEMM: C[M,N] = A[M,K] * B[K,N] (+ epilogue). M%128==0, N%128==0, K%32==0.
// LDS: As[m][k] bf16 (stride 40), Bs[n][k] bf16 (stride 40).
// ---------------------------------------------------------------------------
template <int AL, int BL, int EPM, int TIN, int FIN, int STRIDE, int ICN>
__global__ __launch_bounds__(256) void gemm_k(
    const float* __restrict__ Af, const bf16* __restrict__ Abf,
    const float* __restrict__ amix,
    const float* __restrict__ Bf, const bf16* __restrict__ Bbf,
    float* __restrict__ C, bf16* __restrict__ Cb,
    const float* __restrict__ bias, const float* __restrict__ mul,
    int M, int N, int K)
{
    __shared__ __align__(16) unsigned short As[128 * 40];
    __shared__ __align__(16) unsigned short Bs[128 * 40];
    const int tid = threadIdx.x;
    const int n0 = blockIdx.x * 128;
    const int m0 = blockIdx.y * 128;
    const int wave = tid >> 6, lane = tid & 63;
    const int wr = wave >> 1, wc = wave & 1;   // wave -> 64x64 quadrant
    const int lq = lane >> 4, lr = lane & 15;  // quad, row-in-16

    v4f acc[4][4];
#pragma unroll
    for (int i = 0; i < 4; i++)
#pragma unroll
        for (int j = 0; j < 4; j++) acc[i][j] = v4f{0.f, 0.f, 0.f, 0.f};

    // B_CONV: per-thread column decomposition (fixed n per thread)
    int cv_b = 0, cv_to = 0, cv_fo = 0;
    if constexpr (BL == B_CONV) {
        int n = n0 + (tid & 127);
        cv_b = n / 20480;
        int s = n - cv_b * 20480;
        cv_to = s / 20;
        cv_fo = s - cv_to * 20;
    }

    for (int k0 = 0; k0 < K; k0 += 32) {
        // ---- stage A: 128 x 32 bf16
        if constexpr (AL == A_F32 || AL == A_MIX) {
#pragma unroll
            for (int i = 0; i < 8; i++) {
                int ml = i * 16 + (tid >> 4);
                int kp = tid & 15;
                int m = m0 + ml, k = k0 + kp * 2;
                float2 c = *(const float2*)(Af + (size_t)m * K + k);
                if constexpr (AL == A_MIX) {
                    int u = m & 1023;
                    float2 p = {0.f, 0.f};
                    if (u) p = *(const float2*)(Af + (size_t)(m - 1) * K + k);
                    float a0 = amix[k], a1 = amix[k + 1];
                    c.x = c.x * a0 + p.x * (1.f - a0);
                    c.y = c.y * a1 + p.y * (1.f - a1);
                }
                unsigned int pk = (unsigned int)f2b(c.x) | ((unsigned int)f2b(c.y) << 16);
                *(unsigned int*)&As[ml * 40 + kp * 2] = pk;
            }
        } else {  // A_BF16
#pragma unroll
            for (int i = 0; i < 4; i++) {
                int ml = i * 32 + (tid >> 3);
                int kq = tid & 7;
                int m = m0 + ml, k = k0 + kq * 4;
                ushort4 v = *(const ushort4*)((const unsigned short*)Abf + (size_t)m * K + k);
                *(ushort4*)&As[ml * 40 + kq * 4] = v;
            }
        }
        // ---- stage B: 32 x 128 -> Bs[n][k]
        if constexpr (BL == B_F32) {
#pragma unroll
            for (int i = 0; i < 8; i++) {
                int nl = tid & 127;
                int klp = i * 2 + (tid >> 7);
                int k = k0 + klp * 2, n = n0 + nl;
                float f0 = Bf[(size_t)k * N + n];
                float f1 = Bf[(size_t)(k + 1) * N + n];
                unsigned int pk = (unsigned int)f2b(f0) | ((unsigned int)f2b(f1) << 16);
                *(unsigned int*)&Bs[nl * 40 + klp * 2] = pk;
            }
        } else {  // B_CONV im2col gather
            int nl = tid & 127;
#pragma unroll
            for (int i = 0; i < 16; i++) {
                int kl = i * 2 + (tid >> 7);
                int k = k0 + kl;
                int ic = k / 9;
                int r = k - ic * 9;
                int kt = r / 3, kf = r - kt * 3;
                int ti = cv_to * STRIDE - 1 + kt;
                int fi = cv_fo * STRIDE - 1 + kf;
                unsigned short v = 0;
                if ((unsigned)ti < (unsigned)TIN && (unsigned)fi < (unsigned)FIN)
                    v = ((const unsigned short*)Bbf)[(size_t)cv_b * ((size_t)ICN * TIN * FIN) +
                                                     ((size_t)ic * TIN + ti) * FIN + fi];
                Bs[nl * 40 + kl] = v;
            }
        }
        __syncthreads();

        // ---- fragments + 16 MFMA
        v8bf fa[4], fb[4];
#pragma unroll
        for (int mi = 0; mi < 4; mi++)
            fa[mi] = *(const v8bf*)&As[(wr * 64 + mi * 16 + lr) * 40 + lq * 8];
#pragma unroll
        for (int ni = 0; ni < 4; ni++)
            fb[ni] = *(const v8bf*)&Bs[(wc * 64 + ni * 16 + lr) * 40 + lq * 8];
#pragma unroll
        for (int mi = 0; mi < 4; mi++)
#pragma unroll
            for (int ni = 0; ni < 4; ni++)
                acc[mi][ni] = __builtin_amdgcn_mfma_f32_16x16x32_bf16(
                    fa[mi], fb[ni], acc[mi][ni], 0, 0, 0);
        __syncthreads();
    }

    // ---- epilogue: row = m0+wr*64+mi*16+lq*4+reg, col = n0+wc*64+ni*16+lr
#pragma unroll
    for (int mi = 0; mi < 4; mi++) {
#pragma unroll
        for (int ni = 0; ni < 4; ni++) {
#pragma unroll
            for (int reg = 0; reg < 4; reg++) {
                int row = m0 + wr * 64 + mi * 16 + lq * 4 + reg;
                int col = n0 + wc * 64 + ni * 16 + lr;
                float v = acc[mi][ni][reg];
                if constexpr (EPM == EP_CONV) {
                    v += bias[row];
                    v = v > 0.f ? v : 0.f;
                    int b = col / 20480;
                    int s = col - b * 20480;
                    Cb[(size_t)b * ((size_t)M * 20480) + (size_t)row * 20480 + s] =
                        __float2bfloat16(v);
                } else if constexpr (EPM == EP_CONV_T) {
                    v += bias[row];
                    v = v > 0.f ? v : 0.f;
                    int b = col / 20480;
                    int s = col - b * 20480;
                    int t = s / 20, fo = s - t * 20;
                    Cb[(size_t)(b * 1024 + t) * 10240 + row * 20 + fo] = __float2bfloat16(v);
                } else if constexpr (EPM == EP_BIAS_F32) {
                    C[(size_t)row * N + col] = v + bias[col];
                } else if constexpr (EPM == EP_F32) {
                    C[(size_t)row * N + col] = v;
                } else if constexpr (EPM == EP_SIG) {
                    C[(size_t)row * N + col] = 1.f / (1.f + __expf(-v));
                } else if constexpr (EPM == EP_SQRELU_BF16) {
                    float t = v > 0.f ? v : 0.f;
                    Cb[(size_t)row * N + col] = __float2bfloat16(t * t);
                } else if constexpr (EPM == EP_ADD) {
                    C[(size_t)row * N + col] += v;
                } else if constexpr (EPM == EP_ADDMUL) {
                    size_t idx = (size_t)row * N + col;
                    C[idx] += mul[idx] * v;
                }
            }
        }
    }
}

// ---------------------------------------------------------------------------
// conv1 for a 2-batch chunk: 1 input channel, direct.
// out bf16 (b2, oc, t, f): b*10485760 + oc*81920 + t*40 + f
// ---------------------------------------------------------------------------
__global__ __launch_bounds__(256) void conv1_k(
    const float* __restrict__ x, const float* __restrict__ w,
    const float* __restrict__ bias, bf16* __restrict__ out)
{
    __shared__ float ws_[128 * 9];
    __shared__ float bs_[128];
    const int tid = threadIdx.x;
    for (int i = tid; i < 128 * 9; i += 256) ws_[i] = w[i];
    if (tid < 128) bs_[tid] = bias[tid];
    __syncthreads();

    int idx = blockIdx.x * 256 + tid;  // 2*2048*40 = 163840 total
    int f = idx % 40;
    int t = (idx / 40) & 2047;
    int b = idx / 81920;  // 0..1

    float xin[9];
#pragma unroll
    for (int kt = 0; kt < 3; kt++)
#pragma unroll
        for (int kf = 0; kf < 3; kf++) {
            int ti = 2 * t - 1 + kt, fi = 2 * f - 1 + kf;
            float v = 0.f;
            if ((unsigned)ti < 4096u && (unsigned)fi < 80u)
                v = x[(size_t)b * 327680 + (size_t)ti * 80 + fi];
            xin[kt * 3 + kf] = v;
        }
    size_t obase = (size_t)b * 10485760 + (size_t)t * 40 + f;
    for (int oc = 0; oc < 128; oc++) {
        float a = bs_[oc];
#pragma unroll
        for (int q = 0; q < 9; q++) a += ws_[oc * 9 + q] * xin[q];
        a = a > 0.f ? a : 0.f;
        out[obase + (size_t)oc * 81920] = __float2bfloat16(a);
    }
}

// ---------------------------------------------------------------------------
// LayerNorm over D=512, one wave per row (4 rows / block)
// ---------------------------------------------------------------------------
__global__ __launch_bounds__(256) void ln_k(
    const float* __restrict__ in, float* __restrict__ out,
    const float* __restrict__ g, const float* __restrict__ b, int M)
{
    int wave = threadIdx.x >> 6;
    int lane = threadIdx.x & 63;
    int row = blockIdx.x * 4 + wave;
    if (row >= M) return;
    const float* p = in + (size_t)row * 512;
    float v[8], s = 0.f, sq = 0.f;
#pragma unroll
    for (int i = 0; i < 8; i++) {
        v[i] = p[lane + i * 64];
        s += v[i];
        sq += v[i] * v[i];
    }
#pragma unroll
    for (int o = 32; o > 0; o >>= 1) {
        s += __shfl_xor(s, o, 64);
        sq += __shfl_xor(sq, o, 64);
    }
    float mean = s * (1.f / 512.f);
    float var = sq * (1.f / 512.f) - mean * mean;
    float r = rsqrtf(var + 1e-5f);
    float* q = out + (size_t)row * 512;
#pragma unroll
    for (int i = 0; i < 8; i++) {
        int d = lane + i * 64;
        q[d] = (v[i] - mean) * r * g[d] + b[d];
    }
}

// ---------------------------------------------------------------------------
// WKV sequential scan; one thread per (b,d); out = r*wkv (in-place over r).
// Register-prefetch pipeline; 64 blocks x 64 threads to spread across CUs.
// ---------------------------------------------------------------------------
__global__ __launch_bounds__(64) void wkv_k(
    const float* __restrict__ kbuf, const float* __restrict__ vbuf,
    const float* rbuf, float* outbuf,
    const float* __restrict__ decay, const float* __restrict__ first)
{
    int idx = blockIdx.x * 64 + threadIdx.x;  // 8*512 = 4096
    int d = idx & 511;
    int b = idx >> 9;
    float w = -__expf(decay[d]);
    float u = first[d];
    float aa = 0.f, bb = 0.f, pp = -1e38f;
    size_t base = (size_t)b * 1024 * 512 + d;
    float kt = kbuf[base], vt = vbuf[base], rt = rbuf[base];
    for (int t = 0; t < 1024; t++) {
        size_t o = base + (size_t)t * 512;
        float kn = 0.f, vn = 0.f, rn = 0.f;
        if (t < 1023) {
            size_t o1 = o + 512;
            kn = kbuf[o1]; vn = vbuf[o1]; rn = rbuf[o1];
        }
        float ww = u + kt;
        float p = pp > ww ? pp : ww;
        float e1 = __expf(pp - p), e2 = __expf(ww - p);
        float out = (e1 * aa + e2 * vt) / (e1 * bb + e2);
        outbuf[o] = rt * out;
        float ww2 = pp + w;
        float p2 = ww2 > kt ? ww2 : kt;
        e1 = __expf(ww2 - p2);
        e2 = __expf(kt - p2);
        aa = e1 * aa + e2 * vt;
        bb = e1 * bb + e2;
        pp = p2;
        kt = kn; vt = vn; rt = rn;
    }
}

__global__ void olens_k(const int* __restrict__ x_len, float* __restrict__ out)
{
    int i = threadIdx.x;
    if (i < 8) {
        int l1 = (x_len[i] - 1) / 2 + 1;
        int ol = (l1 - 1) / 2 + 1;
        out[i] = (float)ol;
    }
}

// ---------------------------------------------------------------------------
extern "C" void kernel_launch(void* const* d_in, const int* in_sizes, int n_in,
                              void* d_out, int out_size, void* d_ws, size_t ws_size,
                              hipStream_t stream)
{
    (void)in_sizes; (void)n_in; (void)out_size; (void)ws_size;
    const float* x         = (const float*)d_in[0];
    const int*   x_len     = (const int*)d_in[1];
    const float* conv1_w   = (const float*)d_in[2];
    const float* conv1_b   = (const float*)d_in[3];
    const float* conv2_w   = (const float*)d_in[4];
    const float* conv2_b   = (const float*)d_in[5];
    const float* conv3_w   = (const float*)d_in[6];
    const float* conv3_b   = (const float*)d_in[7];
    const float* embed_w   = (const float*)d_in[8];
    const float* embed_b   = (const float*)d_in[9];
    const float* embed_ln_g= (const float*)d_in[10];
    const float* embed_ln_b= (const float*)d_in[11];
    const float* ln_att_g  = (const float*)d_in[12];
    const float* ln_att_b  = (const float*)d_in[13];
    const float* att_decay = (const float*)d_in[14];
    const float* att_first = (const float*)d_in[15];
    const float* att_mix_k = (const float*)d_in[16];
    const float* att_mix_v = (const float*)d_in[17];
    const float* att_mix_r = (const float*)d_in[18];
    const float* att_wk    = (const float*)d_in[19];
    const float* att_wv    = (const float*)d_in[20];
    const float* att_wr    = (const float*)d_in[21];
    const float* att_wo    = (const float*)d_in[22];
    const float* ln_ffn_g  = (const float*)d_in[23];
    const float* ln_ffn_b  = (const float*)d_in[24];
    const float* ffn_mix_k = (const float*)d_in[25];
    const float* ffn_mix_r = (const float*)d_in[26];
    const float* ffn_wk    = (const float*)d_in[27];
    const float* ffn_wv    = (const float*)d_in[28];
    const float* ffn_wr    = (const float*)d_in[29];
    const float* final_ln_g= (const float*)d_in[30];
    const float* final_ln_b= (const float*)d_in[31];

    // ---- workspace layout (total 132 MB) ----
    // 0    ..16MB : h    (8192x512 f32)
    // 16MB ..32MB : xn   (8192x512 f32)
    // 32MB ..48MB : kb   (8192x512 f32)   | conv phase: c1b bf16 32..72MB
    // 48MB ..64MB : vb                    |             c2b bf16 72..92MB
    // 64MB ..80MB : rb                    |             c3b bf16 92..132MB
    // 80MB ..112MB: kkb  (8192x2048 bf16)
    char* wsb = (char*)d_ws;
    float* h   = (float*)(wsb);
    float* xn  = (float*)(wsb + (16LL << 20));
    float* kb  = (float*)(wsb + (32LL << 20));
    float* vb  = (float*)(wsb + (48LL << 20));
    float* rb  = (float*)(wsb + (64LL << 20));
    bf16*  kkb = (bf16*) (wsb + (80LL << 20));
    bf16*  c1b = (bf16*) (wsb + (32LL << 20));
    bf16*  c2b = (bf16*) (wsb + (72LL << 20));
    bf16*  c3b = (bf16*) (wsb + (92LL << 20));  // token-major (2048 x 10240)

    // ---- conv frontend + embed, 2 batches per chunk
    for (int chunk = 0; chunk < 4; chunk++) {
        int b0 = chunk * 2;
        conv1_k<<<640, 256, 0, stream>>>(x + (size_t)b0 * 327680, conv1_w, conv1_b, c1b);
        gemm_k<A_F32, B_CONV, EP_CONV, 2048, 40, 2, 128><<<dim3(320, 2), 256, 0, stream>>>(
            conv2_w, nullptr, nullptr, nullptr, c1b, nullptr, c2b, conv2_b, nullptr,
            256, 40960, 1152);
        gemm_k<A_F32, B_CONV, EP_CONV_T, 1024, 20, 1, 256><<<dim3(320, 4), 256, 0, stream>>>(
            conv3_w, nullptr, nullptr, nullptr, c2b, nullptr, c3b, conv3_b, nullptr,
            512, 40960, 2304);
        gemm_k<A_BF16, B_F32, EP_BIAS_F32, 0, 0, 0, 0><<<dim3(4, 16), 256, 0, stream>>>(
            nullptr, c3b, nullptr, embed_w, nullptr,
            xn + (size_t)b0 * 1024 * 512, nullptr, embed_b, nullptr,
            2048, 512, 10240);
    }
    ln_k<<<2048, 256, 0, stream>>>(xn, h, embed_ln_g, embed_ln_b, 8192);

    // ---- 4 RWKV blocks
    for (int i = 0; i < 4; i++) {
        // time mixing
        ln_k<<<2048, 256, 0, stream>>>(h, xn, ln_att_g + i * 512, ln_att_b + i * 512, 8192);
        gemm_k<A_MIX, B_F32, EP_F32, 0, 0, 0, 0><<<dim3(4, 64), 256, 0, stream>>>(
            xn, nullptr, att_mix_k + i * 512, att_wk + i * 262144, nullptr,
            kb, nullptr, nullptr, nullptr, 8192, 512, 512);
        gemm_k<A_MIX, B_F32, EP_F32, 0, 0, 0, 0><<<dim3(4, 64), 256, 0, stream>>>(
            xn, nullptr, att_mix_v + i * 512, att_wv + i * 262144, nullptr,
            vb, nullptr, nullptr, nullptr, 8192, 512, 512);
        gemm_k<A_MIX, B_F32, EP_SIG, 0, 0, 0, 0><<<dim3(4, 64), 256, 0, stream>>>(
            xn, nullptr, att_mix_r + i * 512, att_wr + i * 262144, nullptr,
            rb, nullptr, nullptr, nullptr, 8192, 512, 512);
        wkv_k<<<64, 64, 0, stream>>>(kb, vb, rb, rb, att_decay + i * 512, att_first + i * 512);
        gemm_k<A_F32, B_F32, EP_ADD, 0, 0, 0, 0><<<dim3(4, 64), 256, 0, stream>>>(
            rb, nullptr, nullptr, att_wo + i * 262144, nullptr,
            h, nullptr, nullptr, nullptr, 8192, 512, 512);
        // channel mixing
        ln_k<<<2048, 256, 0, stream>>>(h, xn, ln_ffn_g + i * 512, ln_ffn_b + i * 512, 8192);
        gemm_k<A_MIX, B_F32, EP_SQRELU_BF16, 0, 0, 0, 0><<<dim3(16, 64), 256, 0, stream>>>(
            xn, nullptr, ffn_mix_k + i * 512, ffn_wk + i * 1048576, nullptr,
            nullptr, kkb, nullptr, nullptr, 8192, 2048, 512);
        gemm_k<A_MIX, B_F32, EP_SIG, 0, 0, 0, 0><<<dim3(4, 64), 256, 0, stream>>>(
            xn, nullptr, ffn_mix_r + i * 512, ffn_wr + i * 262144, nullptr,
            rb, nullptr, nullptr, nullptr, 8192, 512, 512);
        gemm_k<A_BF16, B_F32, EP_ADDMUL, 0, 0, 0, 0><<<dim3(4, 64), 256, 0, stream>>>(
            nullptr, kkb, nullptr, ffn_wv + i * 1048576, nullptr,
            h, nullptr, nullptr, rb, 8192, 512, 2048);
    }

    // ---- final LN straight into d_out, then olens
    ln_k<<<2048, 256, 0, stream>>>(h, (float*)d_out, final_ln_g, final_ln_b, 8192);
    olens_k<<<1, 64, 0, stream>>>(x_len, (float*)d_out + 4194304);
}

// Round 4
// 5500.780 us; speedup vs baseline: 2.8844x; 1.5771x over previous
//
#include <hip/hip_runtime.h>
#include <hip/hip_bf16.h>

typedef __hip_bfloat16 bf16;
typedef __bf16 v8bf __attribute__((ext_vector_type(8)));
typedef float v4f __attribute__((ext_vector_type(4)));
typedef unsigned short u16x8 __attribute__((ext_vector_type(8)));

// ---------------------------------------------------------------------------
//   x: (8,4096,80) -> conv1(1->128,s2) -> (8,128,2048,40)
//   -> conv2(128->256,s2) -> (8,256,1024,20)
//   -> conv3(256->512,s1) -> tokens (8,1024,10240) [token-major]
//   -> embed GEMM (8192 x 512 x 10240, split-K) -> 4 RWKV blocks -> final LN
// All GEMM operands bf16: weights pre-transposed to [N][K] bf16 at launch.
// GEMM core: bf16 MFMA 16x16x32, 128x128 tile, BK=32, 4 waves/block.
// ---------------------------------------------------------------------------

constexpr int B_T = 0, B_CONV = 1;
constexpr int EP_CONV = 0, EP_CONV_T = 1, EP_ATOMIC = 2, EP_F32 = 3,
              EP_SIG = 4, EP_SQRELU_BF16 = 5, EP_ADD = 6, EP_ADDMUL = 7;

static __device__ __forceinline__ unsigned short f2b(float f) {
    return __builtin_bit_cast(unsigned short, __float2bfloat16(f));
}

// ---------------------------------------------------------------------------
// MFMA GEMM: C[M,N] = A[M,K] * B[K,N]. A bf16 [M][K]; B bf16 [N][K] (B_T) or
// im2col gather (B_CONV). k-range [z*KLEN, (z+1)*KLEN) for split-K.
// ---------------------------------------------------------------------------
template <int BL, int EPM, int TIN, int FIN, int STRIDE, int ICN>
__global__ __launch_bounds__(256) void gemm_k(
    const bf16* __restrict__ A, const bf16* __restrict__ Bw,
    const bf16* __restrict__ Bact,
    float* __restrict__ C, bf16* __restrict__ Cb,
    const float* __restrict__ bias, const float* __restrict__ mul,
    int M, int N, int K, int KLEN)
{
    __shared__ __align__(16) unsigned short As[128 * 40];
    __shared__ __align__(16) unsigned short Bs[128 * 40];
    const int tid = threadIdx.x;
    const int n0 = blockIdx.x * 128;
    const int m0 = blockIdx.y * 128;
    const int kbase = blockIdx.z * KLEN;
    const int wave = tid >> 6, lane = tid & 63;
    const int wr = wave >> 1, wc = wave & 1;   // wave -> 64x64 quadrant
    const int lq = lane >> 4, lr = lane & 15;  // quad, row-in-16

    v4f acc[4][4];
#pragma unroll
    for (int i = 0; i < 4; i++)
#pragma unroll
        for (int j = 0; j < 4; j++) acc[i][j] = v4f{0.f, 0.f, 0.f, 0.f};

    // B_CONV: per-thread column decomposition (fixed n per thread)
    int cv_b = 0, cv_to = 0, cv_fo = 0;
    if constexpr (BL == B_CONV) {
        int n = n0 + (tid & 127);
        cv_b = n / 20480;
        int s = n - cv_b * 20480;
        cv_to = s / 20;
        cv_fo = s - cv_to * 20;
    }

    const int a_ml = (tid >> 2), a_kq = (tid & 3) * 8;

    for (int k0 = kbase; k0 < kbase + KLEN; k0 += 32) {
        // ---- stage A: 128 x 32 bf16, two 16-B loads per thread
#pragma unroll
        for (int i = 0; i < 2; i++) {
            int ml = i * 64 + a_ml;
            *(u16x8*)&As[ml * 40 + a_kq] =
                *(const u16x8*)((const unsigned short*)A + (size_t)(m0 + ml) * K + k0 + a_kq);
        }
        // ---- stage B
        if constexpr (BL == B_T) {
#pragma unroll
            for (int i = 0; i < 2; i++) {
                int nl = i * 64 + a_ml;
                *(u16x8*)&Bs[nl * 40 + a_kq] =
                    *(const u16x8*)((const unsigned short*)Bw + (size_t)(n0 + nl) * K + k0 + a_kq);
            }
        } else {  // B_CONV im2col gather
            int nl = tid & 127;
#pragma unroll
            for (int i = 0; i < 16; i++) {
                int kl = i * 2 + (tid >> 7);
                int k = k0 + kl;
                int ic = k / 9;
                int r = k - ic * 9;
                int kt = r / 3, kf = r - kt * 3;
                int ti = cv_to * STRIDE - 1 + kt;
                int fi = cv_fo * STRIDE - 1 + kf;
                unsigned short v = 0;
                if ((unsigned)ti < (unsigned)TIN && (unsigned)fi < (unsigned)FIN)
                    v = ((const unsigned short*)Bact)[(size_t)cv_b * ((size_t)ICN * TIN * FIN) +
                                                      ((size_t)ic * TIN + ti) * FIN + fi];
                Bs[nl * 40 + kl] = v;
            }
        }
        __syncthreads();

        // ---- fragments + 16 MFMA
        v8bf fa[4], fb[4];
#pragma unroll
        for (int mi = 0; mi < 4; mi++)
            fa[mi] = *(const v8bf*)&As[(wr * 64 + mi * 16 + lr) * 40 + lq * 8];
#pragma unroll
        for (int ni = 0; ni < 4; ni++)
            fb[ni] = *(const v8bf*)&Bs[(wc * 64 + ni * 16 + lr) * 40 + lq * 8];
#pragma unroll
        for (int mi = 0; mi < 4; mi++)
#pragma unroll
            for (int ni = 0; ni < 4; ni++)
                acc[mi][ni] = __builtin_amdgcn_mfma_f32_16x16x32_bf16(
                    fa[mi], fb[ni], acc[mi][ni], 0, 0, 0);
        __syncthreads();
    }

    // ---- epilogue: row = m0+wr*64+mi*16+lq*4+reg, col = n0+wc*64+ni*16+lr
#pragma unroll
    for (int mi = 0; mi < 4; mi++) {
#pragma unroll
        for (int ni = 0; ni < 4; ni++) {
#pragma unroll
            for (int reg = 0; reg < 4; reg++) {
                int row = m0 + wr * 64 + mi * 16 + lq * 4 + reg;
                int col = n0 + wc * 64 + ni * 16 + lr;
                float v = acc[mi][ni][reg];
                if constexpr (EPM == EP_CONV) {
                    v += bias[row];
                    v = v > 0.f ? v : 0.f;
                    int b = col / 20480;
                    int s = col - b * 20480;
                    Cb[(size_t)b * ((size_t)M * 20480) + (size_t)row * 20480 + s] =
                        __float2bfloat16(v);
                } else if constexpr (EPM == EP_CONV_T) {
                    v += bias[row];
                    v = v > 0.f ? v : 0.f;
                    int b = col / 20480;
                    int s = col - b * 20480;
                    int t = s / 20, fo = s - t * 20;
                    Cb[(size_t)(b * 1024 + t) * 10240 + row * 20 + fo] = __float2bfloat16(v);
                } else if constexpr (EPM == EP_ATOMIC) {
                    float add = (blockIdx.z == 0) ? bias[col] : 0.f;
                    atomicAdd(&C[(size_t)row * N + col], v + add);
                } else if constexpr (EPM == EP_F32) {
                    C[(size_t)row * N + col] = v;
                } else if constexpr (EPM == EP_SIG) {
                    C[(size_t)row * N + col] = 1.f / (1.f + __expf(-v));
                } else if constexpr (EPM == EP_SQRELU_BF16) {
                    float t = v > 0.f ? v : 0.f;
                    Cb[(size_t)row * N + col] = __float2bfloat16(t * t);
                } else if constexpr (EPM == EP_ADD) {
                    C[(size_t)row * N + col] += v;
                } else if constexpr (EPM == EP_ADDMUL) {
                    size_t idx = (size_t)row * N + col;
                    C[idx] += mul[idx] * v;
                }
            }
        }
    }
}

// ---------------------------------------------------------------------------
// Prep: f32 -> bf16 copy (row-major kept)
// ---------------------------------------------------------------------------
__global__ __launch_bounds__(256) void cvt_k(const float* __restrict__ in,
                                             bf16* __restrict__ out, int n)
{
    int i = blockIdx.x * 256 + threadIdx.x;
    if (i < n) out[i] = __float2bfloat16(in[i]);
}

// ---------------------------------------------------------------------------
// Prep: f32 [K][N] -> bf16 [N][K]; blockIdx.z selects matrix (stride K*N)
// ---------------------------------------------------------------------------
__global__ __launch_bounds__(256) void transpose_k(const float* __restrict__ in,
                                                   bf16* __restrict__ out, int K, int N)
{
    __shared__ float t[32][33];
    size_t zoff = (size_t)blockIdx.z * K * N;
    int n0 = blockIdx.x * 32, k0 = blockIdx.y * 32;
    int tx = threadIdx.x & 31, ty = threadIdx.x >> 5;  // ty 0..7
#pragma unroll
    for (int i = 0; i < 32; i += 8)
        t[ty + i][tx] = in[zoff + (size_t)(k0 + ty + i) * N + n0 + tx];
    __syncthreads();
#pragma unroll
    for (int i = 0; i < 32; i += 8)
        out[zoff + (size_t)(n0 + ty + i) * K + k0 + tx] = __float2bfloat16(t[tx][ty + i]);
}

// ---------------------------------------------------------------------------
// conv1 for a 2-batch chunk: 1 input channel, direct.
// ---------------------------------------------------------------------------
__global__ __launch_bounds__(256) void conv1_k(
    const float* __restrict__ x, const float* __restrict__ w,
    const float* __restrict__ bias, bf16* __restrict__ out)
{
    __shared__ float ws_[128 * 9];
    __shared__ float bs_[128];
    const int tid = threadIdx.x;
    for (int i = tid; i < 128 * 9; i += 256) ws_[i] = w[i];
    if (tid < 128) bs_[tid] = bias[tid];
    __syncthreads();

    int idx = blockIdx.x * 256 + tid;  // 2*2048*40 = 163840 total
    int f = idx % 40;
    int t = (idx / 40) & 2047;
    int b = idx / 81920;

    float xin[9];
#pragma unroll
    for (int kt = 0; kt < 3; kt++)
#pragma unroll
        for (int kf = 0; kf < 3; kf++) {
            int ti = 2 * t - 1 + kt, fi = 2 * f - 1 + kf;
            float v = 0.f;
            if ((unsigned)ti < 4096u && (unsigned)fi < 80u)
                v = x[(size_t)b * 327680 + (size_t)ti * 80 + fi];
            xin[kt * 3 + kf] = v;
        }
    size_t obase = (size_t)b * 10485760 + (size_t)t * 40 + f;
    for (int oc = 0; oc < 128; oc++) {
        float a = bs_[oc];
#pragma unroll
        for (int q = 0; q < 9; q++) a += ws_[oc * 9 + q] * xin[q];
        a = a > 0.f ? a : 0.f;
        out[obase + (size_t)oc * 81920] = __float2bfloat16(a);
    }
}

// ---------------------------------------------------------------------------
// LayerNorm over D=512, one wave per row (4 rows / block)
// ---------------------------------------------------------------------------
__global__ __launch_bounds__(256) void ln_k(
    const float* __restrict__ in, float* __restrict__ out,
    const float* __restrict__ g, const float* __restrict__ b, int M)
{
    int wave = threadIdx.x >> 6;
    int lane = threadIdx.x & 63;
    int row = blockIdx.x * 4 + wave;
    if (row >= M) return;
    const float* p = in + (size_t)row * 512;
    float v[8], s = 0.f, sq = 0.f;
#pragma unroll
    for (int i = 0; i < 8; i++) {
        v[i] = p[lane + i * 64];
        s += v[i];
        sq += v[i] * v[i];
    }
#pragma unroll
    for (int o = 32; o > 0; o >>= 1) {
        s += __shfl_xor(s, o, 64);
        sq += __shfl_xor(sq, o, 64);
    }
    float mean = s * (1.f / 512.f);
    float var = sq * (1.f / 512.f) - mean * mean;
    float r = rsqrtf(var + 1e-5f);
    float* q = out + (size_t)row * 512;
#pragma unroll
    for (int i = 0; i < 8; i++) {
        int d = lane + i * 64;
        q[d] = (v[i] - mean) * r * g[d] + b[d];
    }
}

// ---------------------------------------------------------------------------
// Token-shift mix -> bf16 operands. idx covers 4 elems (float4/ushort4).
// ---------------------------------------------------------------------------
__global__ __launch_bounds__(256) void mix3_k(
    const float* __restrict__ xn, const float* __restrict__ mk,
    const float* __restrict__ mv, const float* __restrict__ mr,
    bf16* __restrict__ ok, bf16* __restrict__ ov, bf16* __restrict__ orr)
{
    int idx = (blockIdx.x * 256 + threadIdx.x) * 4;  // 8192*512 total
    int d = idx & 511;
    int u = (idx >> 9) & 1023;
    float4 c = *(const float4*)(xn + idx);
    float4 p = {0.f, 0.f, 0.f, 0.f};
    if (u) p = *(const float4*)(xn + idx - 512);
    float4 a;
    ushort4 o;
    a = *(const float4*)(mk + d);
    o.x = f2b(c.x * a.x + p.x * (1.f - a.x)); o.y = f2b(c.y * a.y + p.y * (1.f - a.y));
    o.z = f2b(c.z * a.z + p.z * (1.f - a.z)); o.w = f2b(c.w * a.w + p.w * (1.f - a.w));
    *(ushort4*)((unsigned short*)ok + idx) = o;
    a = *(const float4*)(mv + d);
    o.x = f2b(c.x * a.x + p.x * (1.f - a.x)); o.y = f2b(c.y * a.y + p.y * (1.f - a.y));
    o.z = f2b(c.z * a.z + p.z * (1.f - a.z)); o.w = f2b(c.w * a.w + p.w * (1.f - a.w));
    *(ushort4*)((unsigned short*)ov + idx) = o;
    a = *(const float4*)(mr + d);
    o.x = f2b(c.x * a.x + p.x * (1.f - a.x)); o.y = f2b(c.y * a.y + p.y * (1.f - a.y));
    o.z = f2b(c.z * a.z + p.z * (1.f - a.z)); o.w = f2b(c.w * a.w + p.w * (1.f - a.w));
    *(ushort4*)((unsigned short*)orr + idx) = o;
}

__global__ __launch_bounds__(256) void mix2_k(
    const float* __restrict__ xn, const float* __restrict__ mk,
    const float* __restrict__ mr, bf16* __restrict__ ok, bf16* __restrict__ orr)
{
    int idx = (blockIdx.x * 256 + threadIdx.x) * 4;
    int d = idx & 511;
    int u = (idx >> 9) & 1023;
    float4 c = *(const float4*)(xn + idx);
    float4 p = {0.f, 0.f, 0.f, 0.f};
    if (u) p = *(const float4*)(xn + idx - 512);
    float4 a;
    ushort4 o;
    a = *(const float4*)(mk + d);
    o.x = f2b(c.x * a.x + p.x * (1.f - a.x)); o.y = f2b(c.y * a.y + p.y * (1.f - a.y));
    o.z = f2b(c.z * a.z + p.z * (1.f - a.z)); o.w = f2b(c.w * a.w + p.w * (1.f - a.w));
    *(ushort4*)((unsigned short*)ok + idx) = o;
    a = *(const float4*)(mr + d);
    o.x = f2b(c.x * a.x + p.x * (1.f - a.x)); o.y = f2b(c.y * a.y + p.y * (1.f - a.y));
    o.z = f2b(c.z * a.z + p.z * (1.f - a.z)); o.w = f2b(c.w * a.w + p.w * (1.f - a.w));
    *(ushort4*)((unsigned short*)orr + idx) = o;
}

// ---------------------------------------------------------------------------
// WKV sequential scan; one thread per (b,d); out = bf16(r*wkv).
// ---------------------------------------------------------------------------
__global__ __launch_bounds__(64) void wkv_k(
    const float* __restrict__ kbuf, const float* __restrict__ vbuf,
    const float* __restrict__ rbuf, bf16* __restrict__ outbuf,
    const float* __restrict__ decay, const float* __restrict__ first)
{
    int idx = blockIdx.x * 64 + threadIdx.x;  // 8*512 = 4096
    int d = idx & 511;
    int b = idx >> 9;
    float w = -__expf(decay[d]);
    float u = first[d];
    float aa = 0.f, bb = 0.f, pp = -1e38f;
    size_t base = (size_t)b * 1024 * 512 + d;
    float kt = kbuf[base], vt = vbuf[base], rt = rbuf[base];
    for (int t = 0; t < 1024; t++) {
        size_t o = base + (size_t)t * 512;
        float kn = 0.f, vn = 0.f, rn = 0.f;
        if (t < 1023) {
            size_t o1 = o + 512;
            kn = kbuf[o1]; vn = vbuf[o1]; rn = rbuf[o1];
        }
        float ww = u + kt;
        float p = pp > ww ? pp : ww;
        float e1 = __expf(pp - p), e2 = __expf(ww - p);
        float out = (e1 * aa + e2 * vt) / (e1 * bb + e2);
        outbuf[o] = __float2bfloat16(rt * out);
        float ww2 = pp + w;
        float p2 = ww2 > kt ? ww2 : kt;
        e1 = __expf(ww2 - p2);
        e2 = __expf(kt - p2);
        aa = e1 * aa + e2 * vt;
        bb = e1 * bb + e2;
        pp = p2;
        kt = kn; vt = vn; rt = rn;
    }
}

__global__ void olens_k(const int* __restrict__ x_len, float* __restrict__ out)
{
    int i = threadIdx.x;
    if (i < 8) {
        int l1 = (x_len[i] - 1) / 2 + 1;
        int ol = (l1 - 1) / 2 + 1;
        out[i] = (float)ol;
    }
}

// ---------------------------------------------------------------------------
extern "C" void kernel_launch(void* const* d_in, const int* in_sizes, int n_in,
                              void* d_out, int out_size, void* d_ws, size_t ws_size,
                              hipStream_t stream)
{
    (void)in_sizes; (void)n_in; (void)out_size; (void)ws_size;
    const float* x         = (const float*)d_in[0];
    const int*   x_len     = (const int*)d_in[1];
    const float* conv1_w   = (const float*)d_in[2];
    const float* conv1_b   = (const float*)d_in[3];
    const float* conv2_w   = (const float*)d_in[4];
    const float* conv2_b   = (const float*)d_in[5];
    const float* conv3_w   = (const float*)d_in[6];
    const float* conv3_b   = (const float*)d_in[7];
    const float* embed_w   = (const float*)d_in[8];
    const float* embed_b   = (const float*)d_in[9];
    const float* embed_ln_g= (const float*)d_in[10];
    const float* embed_ln_b= (const float*)d_in[11];
    const float* ln_att_g  = (const float*)d_in[12];
    const float* ln_att_b  = (const float*)d_in[13];
    const float* att_decay = (const float*)d_in[14];
    const float* att_first = (const float*)d_in[15];
    const float* att_mix_k = (const float*)d_in[16];
    const float* att_mix_v = (const float*)d_in[17];
    const float* att_mix_r = (const float*)d_in[18];
    const float* att_wk    = (const float*)d_in[19];
    const float* att_wv    = (const float*)d_in[20];
    const float* att_wr    = (const float*)d_in[21];
    const float* att_wo    = (const float*)d_in[22];
    const float* ln_ffn_g  = (const float*)d_in[23];
    const float* ln_ffn_b  = (const float*)d_in[24];
    const float* ffn_mix_k = (const float*)d_in[25];
    const float* ffn_mix_r = (const float*)d_in[26];
    const float* ffn_wk    = (const float*)d_in[27];
    const float* ffn_wv    = (const float*)d_in[28];
    const float* ffn_wr    = (const float*)d_in[29];
    const float* final_ln_g= (const float*)d_in[30];
    const float* final_ln_b= (const float*)d_in[31];

    // ---- workspace layout (MiB offsets, ~184 MiB total) ----
    // 0..16 h | 16..32 xn | 32..40 rwkvb | 40..48 xkb | 48..56 xvb | 56..64 xrb
    // 64..80 kb | 80..96 vb | 96..112 rb | 112..144 kkb
    // conv phase overlay: c1b 40..80, c2b 80..100, c3b 100..140
    // weights (bf16, persistent per launch): 144..184
    char* wsb = (char*)d_ws;
    float* h     = (float*)(wsb);
    float* xn    = (float*)(wsb + (16LL << 20));
    bf16*  rwkvb = (bf16*) (wsb + (32LL << 20));
    bf16*  xkb   = (bf16*) (wsb + (40LL << 20));
    bf16*  xvb   = (bf16*) (wsb + (48LL << 20));
    bf16*  xrb   = (bf16*) (wsb + (56LL << 20));
    float* kb    = (float*)(wsb + (64LL << 20));
    float* vb    = (float*)(wsb + (80LL << 20));
    float* rb    = (float*)(wsb + (96LL << 20));
    bf16*  kkb   = (bf16*) (wsb + (112LL << 20));
    bf16*  c1b   = (bf16*) (wsb + (40LL << 20));
    bf16*  c2b   = (bf16*) (wsb + (80LL << 20));
    bf16*  c3b   = (bf16*) (wsb + (100LL << 20));
    bf16*  attTk = (bf16*) (wsb + (144LL << 20));  // 4 x [512][512]
    bf16*  attTv = (bf16*) (wsb + (146LL << 20));
    bf16*  attTr = (bf16*) (wsb + (148LL << 20));
    bf16*  attTo = (bf16*) (wsb + (150LL << 20));
    bf16*  ffnTk = (bf16*) (wsb + (152LL << 20));  // 4 x [2048][512]
    bf16*  ffnTv = (bf16*) (wsb + (160LL << 20));  // 4 x [512][2048]
    bf16*  ffnTr = (bf16*) (wsb + (168LL << 20));  // 4 x [512][512]
    bf16*  embT  = (bf16*) (wsb + (170LL << 20));  // [512][10240]
    bf16*  c2wb  = (bf16*) (wsb + (180LL << 20));  // 256x1152
    bf16*  c3wb  = (bf16*) (wsb + (181LL << 20));  // 512x2304

    // ---- weight prep (bf16 convert / transpose)
    transpose_k<<<dim3(16, 16, 4), 256, 0, stream>>>(att_wk, attTk, 512, 512);
    transpose_k<<<dim3(16, 16, 4), 256, 0, stream>>>(att_wv, attTv, 512, 512);
    transpose_k<<<dim3(16, 16, 4), 256, 0, stream>>>(att_wr, attTr, 512, 512);
    transpose_k<<<dim3(16, 16, 4), 256, 0, stream>>>(att_wo, attTo, 512, 512);
    transpose_k<<<dim3(64, 16, 4), 256, 0, stream>>>(ffn_wk, ffnTk, 512, 2048);
    transpose_k<<<dim3(16, 64, 4), 256, 0, stream>>>(ffn_wv, ffnTv, 2048, 512);
    transpose_k<<<dim3(16, 16, 4), 256, 0, stream>>>(ffn_wr, ffnTr, 512, 512);
    transpose_k<<<dim3(16, 320, 1), 256, 0, stream>>>(embed_w, embT, 10240, 512);
    cvt_k<<<1152, 256, 0, stream>>>(conv2_w, c2wb, 294912);
    cvt_k<<<4608, 256, 0, stream>>>(conv3_w, c3wb, 1179648);
    hipMemsetAsync(xn, 0, 16LL << 20, stream);

    // ---- conv frontend + embed (split-K x4, atomic), 2 batches per chunk
    for (int chunk = 0; chunk < 4; chunk++) {
        int b0 = chunk * 2;
        conv1_k<<<640, 256, 0, stream>>>(x + (size_t)b0 * 327680, conv1_w, conv1_b, c1b);
        gemm_k<B_CONV, EP_CONV, 2048, 40, 2, 128><<<dim3(320, 2), 256, 0, stream>>>(
            c2wb, nullptr, c1b, nullptr, c2b, conv2_b, nullptr, 256, 40960, 1152, 1152);
        gemm_k<B_CONV, EP_CONV_T, 1024, 20, 1, 256><<<dim3(320, 4), 256, 0, stream>>>(
            c3wb, nullptr, c2b, nullptr, c3b, conv3_b, nullptr, 512, 40960, 2304, 2304);
        gemm_k<B_T, EP_ATOMIC, 0, 0, 0, 0><<<dim3(4, 16, 4), 256, 0, stream>>>(
            c3b, embT, nullptr, xn + (size_t)b0 * 1024 * 512, nullptr, embed_b, nullptr,
            2048, 512, 10240, 2560);
    }
    ln_k<<<2048, 256, 0, stream>>>(xn, h, embed_ln_g, embed_ln_b, 8192);

    // ---- 4 RWKV blocks
    for (int i = 0; i < 4; i++) {
        // time mixing
        ln_k<<<2048, 256, 0, stream>>>(h, xn, ln_att_g + i * 512, ln_att_b + i * 512, 8192);
        mix3_k<<<4096, 256, 0, stream>>>(xn, att_mix_k + i * 512, att_mix_v + i * 512,
                                         att_mix_r + i * 512, xkb, xvb, xrb);
        gemm_k<B_T, EP_F32, 0, 0, 0, 0><<<dim3(4, 64), 256, 0, stream>>>(
            xkb, attTk + (size_t)i * 262144, nullptr, kb, nullptr, nullptr, nullptr,
            8192, 512, 512, 512);
        gemm_k<B_T, EP_F32, 0, 0, 0, 0><<<dim3(4, 64), 256, 0, stream>>>(
            xvb, attTv + (size_t)i * 262144, nullptr, vb, nullptr, nullptr, nullptr,
            8192, 512, 512, 512);
        gemm_k<B_T, EP_SIG, 0, 0, 0, 0><<<dim3(4, 64), 256, 0, stream>>>(
            xrb, attTr + (size_t)i * 262144, nullptr, rb, nullptr, nullptr, nullptr,
            8192, 512, 512, 512);
        wkv_k<<<64, 64, 0, stream>>>(kb, vb, rb, rwkvb, att_decay + i * 512, att_first + i * 512);
        gemm_k<B_T, EP_ADD, 0, 0, 0, 0><<<dim3(4, 64), 256, 0, stream>>>(
            rwkvb, attTo + (size_t)i * 262144, nullptr, h, nullptr, nullptr, nullptr,
            8192, 512, 512, 512);
        // channel mixing
        ln_k<<<2048, 256, 0, stream>>>(h, xn, ln_ffn_g + i * 512, ln_ffn_b + i * 512, 8192);
        mix2_k<<<4096, 256, 0, stream>>>(xn, ffn_mix_k + i * 512, ffn_mix_r + i * 512, xkb, xrb);
        gemm_k<B_T, EP_SQRELU_BF16, 0, 0, 0, 0><<<dim3(16, 64), 256, 0, stream>>>(
            xkb, ffnTk + (size_t)i * 1048576, nullptr, nullptr, kkb, nullptr, nullptr,
            8192, 2048, 512, 512);
        gemm_k<B_T, EP_SIG, 0, 0, 0, 0><<<dim3(4, 64), 256, 0, stream>>>(
            xrb, ffnTr + (size_t)i * 262144, nullptr, rb, nullptr, nullptr, nullptr,
            8192, 512, 512, 512);
        gemm_k<B_T, EP_ADDMUL, 0, 0, 0, 0><<<dim3(4, 64), 256, 0, stream>>>(
            kkb, ffnTv + (size_t)i * 1048576, nullptr, h, nullptr, nullptr, rb,
            8192, 512, 2048, 2048);
    }

    // ---- final LN straight into d_out, then olens
    ln_k<<<2048, 256, 0, stream>>>(h, (float*)d_out, final_ln_g, final_ln_b, 8192);
    olens_k<<<1, 64, 0, stream>>>(x_len, (float*)d_out + 4194304);
}

// Round 5
// 3235.546 us; speedup vs baseline: 4.9039x; 1.7001x over previous
//
#include <hip/hip_runtime.h>
#include <hip/hip_bf16.h>

typedef __hip_bfloat16 bf16;
typedef __bf16 v8bf __attribute__((ext_vector_type(8)));
typedef float v4f __attribute__((ext_vector_type(4)));
typedef unsigned short u16x8 __attribute__((ext_vector_type(8)));

// ---------------------------------------------------------------------------
//   x: (8,4096,80) -> conv1(1->128,s2) -> (8,2048,40,128)   [channel-last]
//   -> conv2(128->256,s2) -> (8,1024,20,256)                [channel-last]
//   -> conv3(256->512,s1) -> tokens (8,1024,10240)          [token-major]
//   -> embed GEMM (8192 x 512 x 10240, split-K) -> 4 RWKV blocks -> final LN
// Conv weights reordered to [oc][(kt*3+kf)*IC+ic] so im2col B-staging is pure
// 16-B vector loads. GEMM core: bf16 MFMA 16x16x32, 128x128 tile, BK=32.
// ---------------------------------------------------------------------------

constexpr int B_T = 0, B_CONV = 1;
constexpr int EP_CONV_CL = 0, EP_CONV_T = 1, EP_ATOMIC = 2, EP_F32 = 3,
              EP_SIG = 4, EP_SQRELU_BF16 = 5, EP_ADD = 6, EP_ADDMUL = 7;

static __device__ __forceinline__ unsigned short f2b(float f) {
    return __builtin_bit_cast(unsigned short, __float2bfloat16(f));
}

// ---------------------------------------------------------------------------
// MFMA GEMM: C[M,N] = A[M,K] * B[K,N]. A bf16 [M][K]; B bf16 [N][K] (B_T) or
// channel-last im2col gather (B_CONV). k-range [z*KLEN,(z+1)*KLEN) (split-K).
// ---------------------------------------------------------------------------
template <int BL, int EPM, int TIN, int FIN, int STRIDE, int ICN>
__global__ __launch_bounds__(256) void gemm_k(
    const bf16* __restrict__ A, const bf16* __restrict__ Bw,
    const bf16* __restrict__ Bact,
    float* __restrict__ C, bf16* __restrict__ Cb,
    const float* __restrict__ bias, const float* __restrict__ mul,
    int M, int N, int K, int KLEN)
{
    __shared__ __align__(16) unsigned short As[128 * 40];
    __shared__ __align__(16) unsigned short Bs[128 * 40];
    const int tid = threadIdx.x;
    const int n0 = blockIdx.x * 128;
    const int m0 = blockIdx.y * 128;
    const int kbase = blockIdx.z * KLEN;
    const int wave = tid >> 6, lane = tid & 63;
    const int wr = wave >> 1, wc = wave & 1;   // wave -> 64x64 quadrant
    const int lq = lane >> 4, lr = lane & 15;  // quad, row-in-16

    v4f acc[4][4];
#pragma unroll
    for (int i = 0; i < 4; i++)
#pragma unroll
        for (int j = 0; j < 4; j++) acc[i][j] = v4f{0.f, 0.f, 0.f, 0.f};

    // B_CONV: per-thread column decomposition (fixed n per thread)
    int cv_b = 0, cv_to = 0, cv_fo = 0;
    if constexpr (BL == B_CONV) {
        int n = n0 + (tid & 127);
        cv_b = n / 20480;
        int s = n - cv_b * 20480;
        cv_to = s / 20;
        cv_fo = s - cv_to * 20;
    }

    const int a_ml = (tid >> 2), a_kq = (tid & 3) * 8;

    for (int k0 = kbase; k0 < kbase + KLEN; k0 += 32) {
        // ---- stage A: 128 x 32 bf16, two 16-B loads per thread
#pragma unroll
        for (int i = 0; i < 2; i++) {
            int ml = i * 64 + a_ml;
            *(u16x8*)&As[ml * 40 + a_kq] =
                *(const u16x8*)((const unsigned short*)A + (size_t)(m0 + ml) * K + k0 + a_kq);
        }
        // ---- stage B
        if constexpr (BL == B_T) {
#pragma unroll
            for (int i = 0; i < 2; i++) {
                int nl = i * 64 + a_ml;
                *(u16x8*)&Bs[nl * 40 + a_kq] =
                    *(const u16x8*)((const unsigned short*)Bw + (size_t)(n0 + nl) * K + k0 + a_kq);
            }
        } else {  // B_CONV: channel-last im2col, vectorized
            int kg = k0 / ICN;             // kt*3+kf
            int ic0 = k0 - kg * ICN;
            int kt = kg / 3, kf = kg - kt * 3;
            int ti = cv_to * STRIDE - 1 + kt;
            int fi = cv_fo * STRIDE - 1 + kf;
            int nl = tid & 127;
            int kq = (tid >> 7) * 16;
            u16x8 v0 = {0, 0, 0, 0, 0, 0, 0, 0}, v1 = v0;
            if ((unsigned)ti < (unsigned)TIN && (unsigned)fi < (unsigned)FIN) {
                const unsigned short* src = (const unsigned short*)Bact +
                    (((size_t)cv_b * TIN + ti) * FIN + fi) * ICN + ic0 + kq;
                v0 = *(const u16x8*)(src);
                v1 = *(const u16x8*)(src + 8);
            }
            *(u16x8*)&Bs[nl * 40 + kq] = v0;
            *(u16x8*)&Bs[nl * 40 + kq + 8] = v1;
        }
        __syncthreads();

        // ---- fragments + 16 MFMA
        v8bf fa[4], fb[4];
#pragma unroll
        for (int mi = 0; mi < 4; mi++)
            fa[mi] = *(const v8bf*)&As[(wr * 64 + mi * 16 + lr) * 40 + lq * 8];
#pragma unroll
        for (int ni = 0; ni < 4; ni++)
            fb[ni] = *(const v8bf*)&Bs[(wc * 64 + ni * 16 + lr) * 40 + lq * 8];
#pragma unroll
        for (int mi = 0; mi < 4; mi++)
#pragma unroll
            for (int ni = 0; ni < 4; ni++)
                acc[mi][ni] = __builtin_amdgcn_mfma_f32_16x16x32_bf16(
                    fa[mi], fb[ni], acc[mi][ni], 0, 0, 0);
        __syncthreads();
    }

    // ---- epilogue: row = m0+wr*64+mi*16+lq*4+reg, col = n0+wc*64+ni*16+lr
#pragma unroll
    for (int mi = 0; mi < 4; mi++) {
#pragma unroll
        for (int ni = 0; ni < 4; ni++) {
#pragma unroll
            for (int reg = 0; reg < 4; reg++) {
                int row = m0 + wr * 64 + mi * 16 + lq * 4 + reg;
                int col = n0 + wc * 64 + ni * 16 + lr;
                float v = acc[mi][ni][reg];
                if constexpr (EPM == EP_CONV_CL) {
                    v += bias[row];
                    v = v > 0.f ? v : 0.f;
                    // channel-last: out[(col)][row], col == (b*T+t)*F+f
                    Cb[(size_t)col * M + row] = __float2bfloat16(v);
                } else if constexpr (EPM == EP_CONV_T) {
                    v += bias[row];
                    v = v > 0.f ? v : 0.f;
                    int b = col / 20480;
                    int s = col - b * 20480;
                    int t = s / 20, fo = s - t * 20;
                    Cb[(size_t)(b * 1024 + t) * 10240 + row * 20 + fo] = __float2bfloat16(v);
                } else if constexpr (EPM == EP_ATOMIC) {
                    float add = (blockIdx.z == 0) ? bias[col] : 0.f;
                    atomicAdd(&C[(size_t)row * N + col], v + add);
                } else if constexpr (EPM == EP_F32) {
                    C[(size_t)row * N + col] = v;
                } else if constexpr (EPM == EP_SIG) {
                    C[(size_t)row * N + col] = 1.f / (1.f + __expf(-v));
                } else if constexpr (EPM == EP_SQRELU_BF16) {
                    float t = v > 0.f ? v : 0.f;
                    Cb[(size_t)row * N + col] = __float2bfloat16(t * t);
                } else if constexpr (EPM == EP_ADD) {
                    C[(size_t)row * N + col] += v;
                } else if constexpr (EPM == EP_ADDMUL) {
                    size_t idx = (size_t)row * N + col;
                    C[idx] += mul[idx] * v;
                }
            }
        }
    }
}

// ---------------------------------------------------------------------------
// Prep: conv weight OIHW f32 -> bf16 [oc][(kt*3+kf)*IC + ic]
// ---------------------------------------------------------------------------
__global__ __launch_bounds__(256) void reorder_w_k(const float* __restrict__ in,
                                                   bf16* __restrict__ out,
                                                   int OC, int IC)
{
    int idx = blockIdx.x * 256 + threadIdx.x;
    if (idx >= OC * IC * 9) return;
    int oc = idx / (IC * 9);
    int r = idx - oc * (IC * 9);
    int g = r / IC;
    int ic = r - g * IC;
    out[idx] = __float2bfloat16(in[((size_t)oc * IC + ic) * 9 + g]);
}

// ---------------------------------------------------------------------------
// Prep: f32 [K][N] -> bf16 [N][K]; blockIdx.z selects matrix (stride K*N)
// ---------------------------------------------------------------------------
__global__ __launch_bounds__(256) void transpose_k(const float* __restrict__ in,
                                                   bf16* __restrict__ out, int K, int N)
{
    __shared__ float t[32][33];
    size_t zoff = (size_t)blockIdx.z * K * N;
    int n0 = blockIdx.x * 32, k0 = blockIdx.y * 32;
    int tx = threadIdx.x & 31, ty = threadIdx.x >> 5;  // ty 0..7
#pragma unroll
    for (int i = 0; i < 32; i += 8)
        t[ty + i][tx] = in[zoff + (size_t)(k0 + ty + i) * N + n0 + tx];
    __syncthreads();
#pragma unroll
    for (int i = 0; i < 32; i += 8)
        out[zoff + (size_t)(n0 + ty + i) * K + k0 + tx] = __float2bfloat16(t[tx][ty + i]);
}

// ---------------------------------------------------------------------------
// conv1 for a 2-batch chunk: 1 input channel, direct, channel-last output.
// out bf16 (b2, t, f, 128): ((b*2048+t)*40+f)*128 + oc
// ---------------------------------------------------------------------------
__global__ __launch_bounds__(256) void conv1_k(
    const float* __restrict__ x, const float* __restrict__ w,
    const float* __restrict__ bias, bf16* __restrict__ out)
{
    __shared__ float ws_[128 * 9];
    __shared__ float bs_[128];
    const int tid = threadIdx.x;
    for (int i = tid; i < 128 * 9; i += 256) ws_[i] = w[i];
    if (tid < 128) bs_[tid] = bias[tid];
    __syncthreads();

    int idx = blockIdx.x * 256 + tid;  // 2*2048*40 = 163840 total
    int f = idx % 40;
    int t = (idx / 40) & 2047;
    int b = idx / 81920;

    float xin[9];
#pragma unroll
    for (int kt = 0; kt < 3; kt++)
#pragma unroll
        for (int kf = 0; kf < 3; kf++) {
            int ti = 2 * t - 1 + kt, fi = 2 * f - 1 + kf;
            float v = 0.f;
            if ((unsigned)ti < 4096u && (unsigned)fi < 80u)
                v = x[(size_t)b * 327680 + (size_t)ti * 80 + fi];
            xin[kt * 3 + kf] = v;
        }
    unsigned short* outu = (unsigned short*)out + (size_t)idx * 128;
#pragma unroll
    for (int oc8 = 0; oc8 < 16; oc8++) {
        unsigned short pk[8];
#pragma unroll
        for (int j = 0; j < 8; j++) {
            int oc = oc8 * 8 + j;
            float a = bs_[oc];
#pragma unroll
            for (int q = 0; q < 9; q++) a += ws_[oc * 9 + q] * xin[q];
            a = a > 0.f ? a : 0.f;
            pk[j] = f2b(a);
        }
        *(u16x8*)&outu[oc8 * 8] = *(u16x8*)pk;
    }
}

// ---------------------------------------------------------------------------
// LayerNorm over D=512, one wave per row (4 rows / block)
// ---------------------------------------------------------------------------
__global__ __launch_bounds__(256) void ln_k(
    const float* __restrict__ in, float* __restrict__ out,
    const float* __restrict__ g, const float* __restrict__ b, int M)
{
    int wave = threadIdx.x >> 6;
    int lane = threadIdx.x & 63;
    int row = blockIdx.x * 4 + wave;
    if (row >= M) return;
    const float* p = in + (size_t)row * 512;
    float v[8], s = 0.f, sq = 0.f;
#pragma unroll
    for (int i = 0; i < 8; i++) {
        v[i] = p[lane + i * 64];
        s += v[i];
        sq += v[i] * v[i];
    }
#pragma unroll
    for (int o = 32; o > 0; o >>= 1) {
        s += __shfl_xor(s, o, 64);
        sq += __shfl_xor(sq, o, 64);
    }
    float mean = s * (1.f / 512.f);
    float var = sq * (1.f / 512.f) - mean * mean;
    float r = rsqrtf(var + 1e-5f);
    float* q = out + (size_t)row * 512;
#pragma unroll
    for (int i = 0; i < 8; i++) {
        int d = lane + i * 64;
        q[d] = (v[i] - mean) * r * g[d] + b[d];
    }
}

// ---------------------------------------------------------------------------
// Token-shift mix -> bf16 operands. idx covers 4 elems (float4/ushort4).
// ---------------------------------------------------------------------------
__global__ __launch_bounds__(256) void mix3_k(
    const float* __restrict__ xn, const float* __restrict__ mk,
    const float* __restrict__ mv, const float* __restrict__ mr,
    bf16* __restrict__ ok, bf16* __restrict__ ov, bf16* __restrict__ orr)
{
    int idx = (blockIdx.x * 256 + threadIdx.x) * 4;  // 8192*512 total
    int d = idx & 511;
    int u = (idx >> 9) & 1023;
    float4 c = *(const float4*)(xn + idx);
    float4 p = {0.f, 0.f, 0.f, 0.f};
    if (u) p = *(const float4*)(xn + idx - 512);
    float4 a;
    ushort4 o;
    a = *(const float4*)(mk + d);
    o.x = f2b(c.x * a.x + p.x * (1.f - a.x)); o.y = f2b(c.y * a.y + p.y * (1.f - a.y));
    o.z = f2b(c.z * a.z + p.z * (1.f - a.z)); o.w = f2b(c.w * a.w + p.w * (1.f - a.w));
    *(ushort4*)((unsigned short*)ok + idx) = o;
    a = *(const float4*)(mv + d);
    o.x = f2b(c.x * a.x + p.x * (1.f - a.x)); o.y = f2b(c.y * a.y + p.y * (1.f - a.y));
    o.z = f2b(c.z * a.z + p.z * (1.f - a.z)); o.w = f2b(c.w * a.w + p.w * (1.f - a.w));
    *(ushort4*)((unsigned short*)ov + idx) = o;
    a = *(const float4*)(mr + d);
    o.x = f2b(c.x * a.x + p.x * (1.f - a.x)); o.y = f2b(c.y * a.y + p.y * (1.f - a.y));
    o.z = f2b(c.z * a.z + p.z * (1.f - a.z)); o.w = f2b(c.w * a.w + p.w * (1.f - a.w));
    *(ushort4*)((unsigned short*)orr + idx) = o;
}

__global__ __launch_bounds__(256) void mix2_k(
    const float* __restrict__ xn, const float* __restrict__ mk,
    const float* __restrict__ mr, bf16* __restrict__ ok, bf16* __restrict__ orr)
{
    int idx = (blockIdx.x * 256 + threadIdx.x) * 4;
    int d = idx & 511;
    int u = (idx >> 9) & 1023;
    float4 c = *(const float4*)(xn + idx);
    float4 p = {0.f, 0.f, 0.f, 0.f};
    if (u) p = *(const float4*)(xn + idx - 512);
    float4 a;
    ushort4 o;
    a = *(const float4*)(mk + d);
    o.x = f2b(c.x * a.x + p.x * (1.f - a.x)); o.y = f2b(c.y * a.y + p.y * (1.f - a.y));
    o.z = f2b(c.z * a.z + p.z * (1.f - a.z)); o.w = f2b(c.w * a.w + p.w * (1.f - a.w));
    *(ushort4*)((unsigned short*)ok + idx) = o;
    a = *(const float4*)(mr + d);
    o.x = f2b(c.x * a.x + p.x * (1.f - a.x)); o.y = f2b(c.y * a.y + p.y * (1.f - a.y));
    o.z = f2b(c.z * a.z + p.z * (1.f - a.z)); o.w = f2b(c.w * a.w + p.w * (1.f - a.w));
    *(ushort4*)((unsigned short*)orr + idx) = o;
}

// ---------------------------------------------------------------------------
// WKV sequential scan; one thread per (b,d); out = bf16(r*wkv).
// ---------------------------------------------------------------------------
__global__ __launch_bounds__(64) void wkv_k(
    const float* __restrict__ kbuf, const float* __restrict__ vbuf,
    const float* __restrict__ rbuf, bf16* __restrict__ outbuf,
    const float* __restrict__ decay, const float* __restrict__ first)
{
    int idx = blockIdx.x * 64 + threadIdx.x;  // 8*512 = 4096
    int d = idx & 511;
    int b = idx >> 9;
    float w = -__expf(decay[d]);
    float u = first[d];
    float aa = 0.f, bb = 0.f, pp = -1e38f;
    size_t base = (size_t)b * 1024 * 512 + d;
    float kt = kbuf[base], vt = vbuf[base], rt = rbuf[base];
    for (int t = 0; t < 1024; t++) {
        size_t o = base + (size_t)t * 512;
        float kn = 0.f, vn = 0.f, rn = 0.f;
        if (t < 1023) {
            size_t o1 = o + 512;
            kn = kbuf[o1]; vn = vbuf[o1]; rn = rbuf[o1];
        }
        float ww = u + kt;
        float p = pp > ww ? pp : ww;
        float e1 = __expf(pp - p), e2 = __expf(ww - p);
        float out = (e1 * aa + e2 * vt) / (e1 * bb + e2);
        outbuf[o] = __float2bfloat16(rt * out);
        float ww2 = pp + w;
        float p2 = ww2 > kt ? ww2 : kt;
        e1 = __expf(ww2 - p2);
        e2 = __expf(kt - p2);
        aa = e1 * aa + e2 * vt;
        bb = e1 * bb + e2;
        pp = p2;
        kt = kn; vt = vn; rt = rn;
    }
}

__global__ void olens_k(const int* __restrict__ x_len, float* __restrict__ out)
{
    int i = threadIdx.x;
    if (i < 8) {
        int l1 = (x_len[i] - 1) / 2 + 1;
        int ol = (l1 - 1) / 2 + 1;
        out[i] = (float)ol;
    }
}

// ---------------------------------------------------------------------------
extern "C" void kernel_launch(void* const* d_in, const int* in_sizes, int n_in,
                              void* d_out, int out_size, void* d_ws, size_t ws_size,
                              hipStream_t stream)
{
    (void)in_sizes; (void)n_in; (void)out_size; (void)ws_size;
    const float* x         = (const float*)d_in[0];
    const int*   x_len     = (const int*)d_in[1];
    const float* conv1_w   = (const float*)d_in[2];
    const float* conv1_b   = (const float*)d_in[3];
    const float* conv2_w   = (const float*)d_in[4];
    const float* conv2_b   = (const float*)d_in[5];
    const float* conv3_w   = (const float*)d_in[6];
    const float* conv3_b   = (const float*)d_in[7];
    const float* embed_w   = (const float*)d_in[8];
    const float* embed_b   = (const float*)d_in[9];
    const float* embed_ln_g= (const float*)d_in[10];
    const float* embed_ln_b= (const float*)d_in[11];
    const float* ln_att_g  = (const float*)d_in[12];
    const float* ln_att_b  = (const float*)d_in[13];
    const float* att_decay = (const float*)d_in[14];
    const float* att_first = (const float*)d_in[15];
    const float* att_mix_k = (const float*)d_in[16];
    const float* att_mix_v = (const float*)d_in[17];
    const float* att_mix_r = (const float*)d_in[18];
    const float* att_wk    = (const float*)d_in[19];
    const float* att_wv    = (const float*)d_in[20];
    const float* att_wr    = (const float*)d_in[21];
    const float* att_wo    = (const float*)d_in[22];
    const float* ln_ffn_g  = (const float*)d_in[23];
    const float* ln_ffn_b  = (const float*)d_in[24];
    const float* ffn_mix_k = (const float*)d_in[25];
    const float* ffn_mix_r = (const float*)d_in[26];
    const float* ffn_wk    = (const float*)d_in[27];
    const float* ffn_wv    = (const float*)d_in[28];
    const float* ffn_wr    = (const float*)d_in[29];
    const float* final_ln_g= (const float*)d_in[30];
    const float* final_ln_b= (const float*)d_in[31];

    // ---- workspace layout (MiB offsets, ~184 MiB total) ----
    // 0..16 h | 16..32 xn | 32..40 rwkvb | 40..48 xkb | 48..56 xvb | 56..64 xrb
    // 64..80 kb | 80..96 vb | 96..112 rb | 112..144 kkb
    // conv phase overlay: c1b 40..80, c2b 80..100, c3b 100..140
    // weights (bf16, persistent per launch): 144..184
    char* wsb = (char*)d_ws;
    float* h     = (float*)(wsb);
    float* xn    = (float*)(wsb + (16LL << 20));
    bf16*  rwkvb = (bf16*) (wsb + (32LL << 20));
    bf16*  xkb   = (bf16*) (wsb + (40LL << 20));
    bf16*  xvb   = (bf16*) (wsb + (48LL << 20));
    bf16*  xrb   = (bf16*) (wsb + (56LL << 20));
    float* kb    = (float*)(wsb + (64LL << 20));
    float* vb    = (float*)(wsb + (80LL << 20));
    float* rb    = (float*)(wsb + (96LL << 20));
    bf16*  kkb   = (bf16*) (wsb + (112LL << 20));
    bf16*  c1b   = (bf16*) (wsb + (40LL << 20));   // (2,2048,40,128) channel-last
    bf16*  c2b   = (bf16*) (wsb + (80LL << 20));   // (2,1024,20,256) channel-last
    bf16*  c3b   = (bf16*) (wsb + (100LL << 20));  // (2048,10240) token-major
    bf16*  attTk = (bf16*) (wsb + (144LL << 20));  // 4 x [512][512]
    bf16*  attTv = (bf16*) (wsb + (146LL << 20));
    bf16*  attTr = (bf16*) (wsb + (148LL << 20));
    bf16*  attTo = (bf16*) (wsb + (150LL << 20));
    bf16*  ffnTk = (bf16*) (wsb + (152LL << 20));  // 4 x [2048][512]
    bf16*  ffnTv = (bf16*) (wsb + (160LL << 20));  // 4 x [512][2048]
    bf16*  ffnTr = (bf16*) (wsb + (168LL << 20));  // 4 x [512][512]
    bf16*  embT  = (bf16*) (wsb + (170LL << 20));  // [512][10240]
    bf16*  c2wb  = (bf16*) (wsb + (180LL << 20));  // 256 x 1152 (reordered)
    bf16*  c3wb  = (bf16*) (wsb + (181LL << 20));  // 512 x 2304 (reordered)

    // ---- weight prep (bf16 convert / transpose / reorder)
    transpose_k<<<dim3(16, 16, 4), 256, 0, stream>>>(att_wk, attTk, 512, 512);
    transpose_k<<<dim3(16, 16, 4), 256, 0, stream>>>(att_wv, attTv, 512, 512);
    transpose_k<<<dim3(16, 16, 4), 256, 0, stream>>>(att_wr, attTr, 512, 512);
    transpose_k<<<dim3(16, 16, 4), 256, 0, stream>>>(att_wo, attTo, 512, 512);
    transpose_k<<<dim3(64, 16, 4), 256, 0, stream>>>(ffn_wk, ffnTk, 512, 2048);
    transpose_k<<<dim3(16, 64, 4), 256, 0, stream>>>(ffn_wv, ffnTv, 2048, 512);
    transpose_k<<<dim3(16, 16, 4), 256, 0, stream>>>(ffn_wr, ffnTr, 512, 512);
    transpose_k<<<dim3(16, 320, 1), 256, 0, stream>>>(embed_w, embT, 10240, 512);
    reorder_w_k<<<1152, 256, 0, stream>>>(conv2_w, c2wb, 256, 128);
    reorder_w_k<<<4608, 256, 0, stream>>>(conv3_w, c3wb, 512, 256);
    hipMemsetAsync(xn, 0, 16LL << 20, stream);

    // ---- conv frontend + embed (split-K x4, atomic), 2 batches per chunk
    for (int chunk = 0; chunk < 4; chunk++) {
        int b0 = chunk * 2;
        conv1_k<<<640, 256, 0, stream>>>(x + (size_t)b0 * 327680, conv1_w, conv1_b, c1b);
        gemm_k<B_CONV, EP_CONV_CL, 2048, 40, 2, 128><<<dim3(320, 2), 256, 0, stream>>>(
            c2wb, nullptr, c1b, nullptr, c2b, conv2_b, nullptr, 256, 40960, 1152, 1152);
        gemm_k<B_CONV, EP_CONV_T, 1024, 20, 1, 256><<<dim3(320, 4), 256, 0, stream>>>(
            c3wb, nullptr, c2b, nullptr, c3b, conv3_b, nullptr, 512, 40960, 2304, 2304);
        gemm_k<B_T, EP_ATOMIC, 0, 0, 0, 0><<<dim3(4, 16, 4), 256, 0, stream>>>(
            c3b, embT, nullptr, xn + (size_t)b0 * 1024 * 512, nullptr, embed_b, nullptr,
            2048, 512, 10240, 2560);
    }
    ln_k<<<2048, 256, 0, stream>>>(xn, h, embed_ln_g, embed_ln_b, 8192);

    // ---- 4 RWKV blocks
    for (int i = 0; i < 4; i++) {
        // time mixing
        ln_k<<<2048, 256, 0, stream>>>(h, xn, ln_att_g + i * 512, ln_att_b + i * 512, 8192);
        mix3_k<<<4096, 256, 0, stream>>>(xn, att_mix_k + i * 512, att_mix_v + i * 512,
                                         att_mix_r + i * 512, xkb, xvb, xrb);
        gemm_k<B_T, EP_F32, 0, 0, 0, 0><<<dim3(4, 64), 256, 0, stream>>>(
            xkb, attTk + (size_t)i * 262144, nullptr, kb, nullptr, nullptr, nullptr,
            8192, 512, 512, 512);
        gemm_k<B_T, EP_F32, 0, 0, 0, 0><<<dim3(4, 64), 256, 0, stream>>>(
            xvb, attTv + (size_t)i * 262144, nullptr, vb, nullptr, nullptr, nullptr,
            8192, 512, 512, 512);
        gemm_k<B_T, EP_SIG, 0, 0, 0, 0><<<dim3(4, 64), 256, 0, stream>>>(
            xrb, attTr + (size_t)i * 262144, nullptr, rb, nullptr, nullptr, nullptr,
            8192, 512, 512, 512);
        wkv_k<<<64, 64, 0, stream>>>(kb, vb, rb, rwkvb, att_decay + i * 512, att_first + i * 512);
        gemm_k<B_T, EP_ADD, 0, 0, 0, 0><<<dim3(4, 64), 256, 0, stream>>>(
            rwkvb, attTo + (size_t)i * 262144, nullptr, h, nullptr, nullptr, nullptr,
            8192, 512, 512, 512);
        // channel mixing
        ln_k<<<2048, 256, 0, stream>>>(h, xn, ln_ffn_g + i * 512, ln_ffn_b + i * 512, 8192);
        mix2_k<<<4096, 256, 0, stream>>>(xn, ffn_mix_k + i * 512, ffn_mix_r + i * 512, xkb, xrb);
        gemm_k<B_T, EP_SQRELU_BF16, 0, 0, 0, 0><<<dim3(16, 64), 256, 0, stream>>>(
            xkb, ffnTk + (size_t)i * 1048576, nullptr, nullptr, kkb, nullptr, nullptr,
            8192, 2048, 512, 512);
        gemm_k<B_T, EP_SIG, 0, 0, 0, 0><<<dim3(4, 64), 256, 0, stream>>>(
            xrb, ffnTr + (size_t)i * 262144, nullptr, rb, nullptr, nullptr, nullptr,
            8192, 512, 512, 512);
        gemm_k<B_T, EP_ADDMUL, 0, 0, 0, 0><<<dim3(4, 64), 256, 0, stream>>>(
            kkb, ffnTv + (size_t)i * 1048576, nullptr, h, nullptr, nullptr, rb,
            8192, 512, 2048, 2048);
    }

    // ---- final LN straight into d_out, then olens
    ln_k<<<2048, 256, 0, stream>>>(h, (float*)d_out, final_ln_g, final_ln_b, 8192);
    olens_k<<<1, 64, 0, stream>>>(x_len, (float*)d_out + 4194304);
}

// Round 6
// 2889.457 us; speedup vs baseline: 5.4912x; 1.1198x over previous
//
#include <hip/hip_runtime.h>
#include <hip/hip_bf16.h>

typedef __hip_bfloat16 bf16;
typedef __bf16 v8bf __attribute__((ext_vector_type(8)));
typedef float v4f __attribute__((ext_vector_type(4)));
typedef unsigned short u16x8 __attribute__((ext_vector_type(8)));

// ---------------------------------------------------------------------------
//   x: (8,4096,80) -> conv1(1->128,s2) -> (8,2048,40,128)   [channel-last]
//   -> conv2(128->256,s2) -> halo (8,1026,22,256)           [channel-last+halo]
//   -> conv3(256->512,s1) -> tokens (8,1024,10240)          [token-major]
//   -> embed GEMM (split-K) -> 4 RWKV blocks -> final LN
// GEMM core: bf16 MFMA 16x16x32, TM x 128 tile (TM=64 for transformer GEMMs
// to get >=2 blocks/CU), BK=32. k/v/r and ffn wk/wr fused into single
// dispatches with packed [N][K] weights.
// ---------------------------------------------------------------------------

constexpr int B_T = 0, B_CONV = 1;
constexpr int EP_CONV_CL = 0, EP_CONV_T = 1, EP_ATOMIC = 2, EP_KVR = 3,
              EP_ADD = 4, EP_FFN = 5, EP_ADDMUL = 6;

static __device__ __forceinline__ unsigned short f2b(float f) {
    return __builtin_bit_cast(unsigned short, __float2bfloat16(f));
}

// ---------------------------------------------------------------------------
// MFMA GEMM: C[M,N] = A[M,K] * B[K,N]. A bf16 [M][K]; B bf16 [N][K] (B_T) or
// channel-last im2col gather (B_CONV; HALO=1 -> unconditional loads from the
// zero-padded (b,1026,22,256) buffer). ASH>0: A += (n0>>ASH)*M*K (fused ops).
// ---------------------------------------------------------------------------
template <int TM, int BL, int EPM, int ASH, int TIN, int FIN, int STRIDE,
          int ICN, int HALO>
__global__ __launch_bounds__(256) void gemm_k(
    const bf16* __restrict__ A, const bf16* __restrict__ Bw,
    const bf16* __restrict__ Bact,
    float* __restrict__ C, bf16* __restrict__ Cb,
    const float* __restrict__ bias, const float* __restrict__ mul,
    int M, int N, int K, int KLEN)
{
    constexpr int MI = TM / 32;
    __shared__ __align__(16) unsigned short As[TM * 40];
    __shared__ __align__(16) unsigned short Bs[128 * 40];
    const int tid = threadIdx.x;
    const int n0 = blockIdx.x * 128;
    const int m0 = blockIdx.y * TM;
    const int kbase = blockIdx.z * KLEN;
    const int wave = tid >> 6, lane = tid & 63;
    const int wr = wave >> 1, wc = wave & 1;
    const int lq = lane >> 4, lr = lane & 15;

    if constexpr (ASH > 0) A += (size_t)(n0 >> ASH) * M * K;

    v4f acc[MI][4];
#pragma unroll
    for (int i = 0; i < MI; i++)
#pragma unroll
        for (int j = 0; j < 4; j++) acc[i][j] = v4f{0.f, 0.f, 0.f, 0.f};

    int cv_b = 0, cv_to = 0, cv_fo = 0;
    if constexpr (BL == B_CONV) {
        int n = n0 + (tid & 127);
        cv_b = n / 20480;
        int s = n - cv_b * 20480;
        cv_to = s / 20;
        cv_fo = s - cv_to * 20;
    }

    const int a_ml = (tid >> 2), a_kq = (tid & 3) * 8;

    for (int k0 = kbase; k0 < kbase + KLEN; k0 += 32) {
        // ---- stage A: TM x 32 bf16, 16-B loads
#pragma unroll
        for (int i = 0; i < TM / 64; i++) {
            int ml = i * 64 + a_ml;
            *(u16x8*)&As[ml * 40 + a_kq] =
                *(const u16x8*)((const unsigned short*)A + (size_t)(m0 + ml) * K + k0 + a_kq);
        }
        // ---- stage B
        if constexpr (BL == B_T) {
#pragma unroll
            for (int i = 0; i < 2; i++) {
                int nl = i * 64 + a_ml;
                *(u16x8*)&Bs[nl * 40 + a_kq] =
                    *(const u16x8*)((const unsigned short*)Bw + (size_t)(n0 + nl) * K + k0 + a_kq);
            }
        } else {
            int kg = k0 / ICN;             // kt*3+kf
            int ic0 = k0 - kg * ICN;
            int kt = kg / 3, kf = kg - kt * 3;
            int nl = tid & 127;
            int kq = (tid >> 7) * 16;
            if constexpr (HALO) {          // conv3: zero-padded input, no branch
                const unsigned short* src = (const unsigned short*)Bact +
                    (((size_t)cv_b * 1026 + cv_to + kt) * 22 + cv_fo + kf) * 256 + ic0 + kq;
                *(u16x8*)&Bs[nl * 40 + kq] = *(const u16x8*)src;
                *(u16x8*)&Bs[nl * 40 + kq + 8] = *(const u16x8*)(src + 8);
            } else {
                int ti = cv_to * STRIDE - 1 + kt;
                int fi = cv_fo * STRIDE - 1 + kf;
                u16x8 v0 = {0, 0, 0, 0, 0, 0, 0, 0}, v1 = v0;
                if ((unsigned)ti < (unsigned)TIN && (unsigned)fi < (unsigned)FIN) {
                    const unsigned short* src = (const unsigned short*)Bact +
                        (((size_t)cv_b * TIN + ti) * FIN + fi) * ICN + ic0 + kq;
                    v0 = *(const u16x8*)(src);
                    v1 = *(const u16x8*)(src + 8);
                }
                *(u16x8*)&Bs[nl * 40 + kq] = v0;
                *(u16x8*)&Bs[nl * 40 + kq + 8] = v1;
            }
        }
        __syncthreads();

        v8bf fa[MI], fb[4];
#pragma unroll
        for (int mi = 0; mi < MI; mi++)
            fa[mi] = *(const v8bf*)&As[(wr * (TM / 2) + mi * 16 + lr) * 40 + lq * 8];
#pragma unroll
        for (int ni = 0; ni < 4; ni++)
            fb[ni] = *(const v8bf*)&Bs[(wc * 64 + ni * 16 + lr) * 40 + lq * 8];
#pragma unroll
        for (int mi = 0; mi < MI; mi++)
#pragma unroll
            for (int ni = 0; ni < 4; ni++)
                acc[mi][ni] = __builtin_amdgcn_mfma_f32_16x16x32_bf16(
                    fa[mi], fb[ni], acc[mi][ni], 0, 0, 0);
        __syncthreads();
    }

    // ---- epilogue
#pragma unroll
    for (int mi = 0; mi < MI; mi++) {
#pragma unroll
        for (int ni = 0; ni < 4; ni++) {
#pragma unroll
            for (int reg = 0; reg < 4; reg++) {
                int row = m0 + wr * (TM / 2) + mi * 16 + lq * 4 + reg;
                int col = n0 + wc * 64 + ni * 16 + lr;
                float v = acc[mi][ni][reg];
                if constexpr (EPM == EP_CONV_CL) {
                    v += bias[row];
                    v = v > 0.f ? v : 0.f;
                    int b = col / 20480;
                    int s = col - b * 20480;
                    int t = s / 20, fo = s - t * 20;
                    Cb[(((size_t)b * 1026 + t + 1) * 22 + fo + 1) * 256 + row] =
                        __float2bfloat16(v);
                } else if constexpr (EPM == EP_CONV_T) {
                    v += bias[row];
                    v = v > 0.f ? v : 0.f;
                    int b = col / 20480;
                    int s = col - b * 20480;
                    int t = s / 20, fo = s - t * 20;
                    Cb[(size_t)(b * 1024 + t) * 10240 + row * 20 + fo] = __float2bfloat16(v);
                } else if constexpr (EPM == EP_ATOMIC) {
                    float add = (blockIdx.z == 0) ? bias[col] : 0.f;
                    atomicAdd(&C[(size_t)row * N + col], v + add);
                } else if constexpr (EPM == EP_KVR) {
                    int seg = col >> 9;     // 0=k,1=v,2=r (uniform per block)
                    if (seg == 2) v = 1.f / (1.f + __expf(-v));
                    C[(size_t)seg * M * 512 + (size_t)row * 512 + (col & 511)] = v;
                } else if constexpr (EPM == EP_ADD) {
                    C[(size_t)row * N + col] += v;
                } else if constexpr (EPM == EP_FFN) {
                    if (col < 2048) {       // wk branch: sqrelu -> bf16 kkb
                        float t = v > 0.f ? v : 0.f;
                        Cb[(size_t)row * 2048 + col] = __float2bfloat16(t * t);
                    } else {                // wr branch: sigmoid -> f32 rb
                        C[(size_t)row * 512 + (col - 2048)] = 1.f / (1.f + __expf(-v));
                    }
                } else if constexpr (EPM == EP_ADDMUL) {
                    size_t idx = (size_t)row * N + col;
                    C[idx] += mul[idx] * v;
                }
            }
        }
    }
}

// ---------------------------------------------------------------------------
// Prep: conv weight OIHW f32 -> bf16 [oc][(kt*3+kf)*IC + ic]
// ---------------------------------------------------------------------------
__global__ __launch_bounds__(256) void reorder_w_k(const float* __restrict__ in,
                                                   bf16* __restrict__ out,
                                                   int OC, int IC)
{
    int idx = blockIdx.x * 256 + threadIdx.x;
    if (idx >= OC * IC * 9) return;
    int oc = idx / (IC * 9);
    int r = idx - oc * (IC * 9);
    int g = r / IC;
    int ic = r - g * IC;
    out[idx] = __float2bfloat16(in[((size_t)oc * IC + ic) * 9 + g]);
}

// ---------------------------------------------------------------------------
// Prep: f32 [K][N] -> bf16 [N][K]; z: in stride K*N, out stride ozs
// ---------------------------------------------------------------------------
__global__ __launch_bounds__(256) void transpose_k(const float* __restrict__ in,
                                                   bf16* __restrict__ out,
                                                   int K, int N, size_t ozs)
{
    __shared__ float t[32][33];
    const float* pin = in + (size_t)blockIdx.z * K * N;
    bf16* pout = out + (size_t)blockIdx.z * ozs;
    int n0 = blockIdx.x * 32, k0 = blockIdx.y * 32;
    int tx = threadIdx.x & 31, ty = threadIdx.x >> 5;
#pragma unroll
    for (int i = 0; i < 32; i += 8)
        t[ty + i][tx] = pin[(size_t)(k0 + ty + i) * N + n0 + tx];
    __syncthreads();
#pragma unroll
    for (int i = 0; i < 32; i += 8)
        pout[(size_t)(n0 + ty + i) * K + k0 + tx] = __float2bfloat16(t[tx][ty + i]);
}

// ---------------------------------------------------------------------------
// conv1 for a 2-batch chunk: 1 input channel, direct, channel-last output.
// ---------------------------------------------------------------------------
__global__ __launch_bounds__(256) void conv1_k(
    const float* __restrict__ x, const float* __restrict__ w,
    const float* __restrict__ bias, bf16* __restrict__ out)
{
    __shared__ float ws_[128 * 9];
    __shared__ float bs_[128];
    const int tid = threadIdx.x;
    for (int i = tid; i < 128 * 9; i += 256) ws_[i] = w[i];
    if (tid < 128) bs_[tid] = bias[tid];
    __syncthreads();

    int idx = blockIdx.x * 256 + tid;  // 2*2048*40
    int f = idx % 40;
    int t = (idx / 40) & 2047;
    int b = idx / 81920;

    float xin[9];
#pragma unroll
    for (int kt = 0; kt < 3; kt++)
#pragma unroll
        for (int kf = 0; kf < 3; kf++) {
            int ti = 2 * t - 1 + kt, fi = 2 * f - 1 + kf;
            float v = 0.f;
            if ((unsigned)ti < 4096u && (unsigned)fi < 80u)
                v = x[(size_t)b * 327680 + (size_t)ti * 80 + fi];
            xin[kt * 3 + kf] = v;
        }
    unsigned short* outu = (unsigned short*)out + (size_t)idx * 128;
#pragma unroll
    for (int oc8 = 0; oc8 < 16; oc8++) {
        unsigned short pk[8];
#pragma unroll
        for (int j = 0; j < 8; j++) {
            int oc = oc8 * 8 + j;
            float a = bs_[oc];
#pragma unroll
            for (int q = 0; q < 9; q++) a += ws_[oc * 9 + q] * xin[q];
            a = a > 0.f ? a : 0.f;
            pk[j] = f2b(a);
        }
        *(u16x8*)&outu[oc8 * 8] = *(u16x8*)pk;
    }
}

// ---------------------------------------------------------------------------
// LayerNorm over D=512, one wave per row (4 rows / block)
// ---------------------------------------------------------------------------
__global__ __launch_bounds__(256) void ln_k(
    const float* __restrict__ in, float* __restrict__ out,
    const float* __restrict__ g, const float* __restrict__ b, int M)
{
    int wave = threadIdx.x >> 6;
    int lane = threadIdx.x & 63;
    int row = blockIdx.x * 4 + wave;
    if (row >= M) return;
    const float* p = in + (size_t)row * 512;
    float v[8], s = 0.f, sq = 0.f;
#pragma unroll
    for (int i = 0; i < 8; i++) {
        v[i] = p[lane + i * 64];
        s += v[i];
        sq += v[i] * v[i];
    }
#pragma unroll
    for (int o = 32; o > 0; o >>= 1) {
        s += __shfl_xor(s, o, 64);
        sq += __shfl_xor(sq, o, 64);
    }
    float mean = s * (1.f / 512.f);
    float var = sq * (1.f / 512.f) - mean * mean;
    float r = rsqrtf(var + 1e-5f);
    float* q = out + (size_t)row * 512;
#pragma unroll
    for (int i = 0; i < 8; i++) {
        int d = lane + i * 64;
        q[d] = (v[i] - mean) * r * g[d] + b[d];
    }
}

// ---------------------------------------------------------------------------
// Token-shift mix -> bf16 operands (4 elems per thread)
// ---------------------------------------------------------------------------
__global__ __launch_bounds__(256) void mix3_k(
    const float* __restrict__ xn, const float* __restrict__ mk,
    const float* __restrict__ mv, const float* __restrict__ mr,
    bf16* __restrict__ ok, bf16* __restrict__ ov, bf16* __restrict__ orr)
{
    int idx = (blockIdx.x * 256 + threadIdx.x) * 4;
    int d = idx & 511;
    int u = (idx >> 9) & 1023;
    float4 c = *(const float4*)(xn + idx);
    float4 p = {0.f, 0.f, 0.f, 0.f};
    if (u) p = *(const float4*)(xn + idx - 512);
    float4 a;
    ushort4 o;
    a = *(const float4*)(mk + d);
    o.x = f2b(c.x * a.x + p.x * (1.f - a.x)); o.y = f2b(c.y * a.y + p.y * (1.f - a.y));
    o.z = f2b(c.z * a.z + p.z * (1.f - a.z)); o.w = f2b(c.w * a.w + p.w * (1.f - a.w));
    *(ushort4*)((unsigned short*)ok + idx) = o;
    a = *(const float4*)(mv + d);
    o.x = f2b(c.x * a.x + p.x * (1.f - a.x)); o.y = f2b(c.y * a.y + p.y * (1.f - a.y));
    o.z = f2b(c.z * a.z + p.z * (1.f - a.z)); o.w = f2b(c.w * a.w + p.w * (1.f - a.w));
    *(ushort4*)((unsigned short*)ov + idx) = o;
    a = *(const float4*)(mr + d);
    o.x = f2b(c.x * a.x + p.x * (1.f - a.x)); o.y = f2b(c.y * a.y + p.y * (1.f - a.y));
    o.z = f2b(c.z * a.z + p.z * (1.f - a.z)); o.w = f2b(c.w * a.w + p.w * (1.f - a.w));
    *(ushort4*)((unsigned short*)orr + idx) = o;
}

__global__ __launch_bounds__(256) void mix2_k(
    const float* __restrict__ xn, const float* __restrict__ mk,
    const float* __restrict__ mr, bf16* __restrict__ ok, bf16* __restrict__ orr)
{
    int idx = (blockIdx.x * 256 + threadIdx.x) * 4;
    int d = idx & 511;
    int u = (idx >> 9) & 1023;
    float4 c = *(const float4*)(xn + idx);
    float4 p = {0.f, 0.f, 0.f, 0.f};
    if (u) p = *(const float4*)(xn + idx - 512);
    float4 a;
    ushort4 o;
    a = *(const float4*)(mk + d);
    o.x = f2b(c.x * a.x + p.x * (1.f - a.x)); o.y = f2b(c.y * a.y + p.y * (1.f - a.y));
    o.z = f2b(c.z * a.z + p.z * (1.f - a.z)); o.w = f2b(c.w * a.w + p.w * (1.f - a.w));
    *(ushort4*)((unsigned short*)ok + idx) = o;
    a = *(const float4*)(mr + d);
    o.x = f2b(c.x * a.x + p.x * (1.f - a.x)); o.y = f2b(c.y * a.y + p.y * (1.f - a.y));
    o.z = f2b(c.z * a.z + p.z * (1.f - a.z)); o.w = f2b(c.w * a.w + p.w * (1.f - a.w));
    *(ushort4*)((unsigned short*)orr + idx) = o;
}

// ---------------------------------------------------------------------------
// WKV sequential scan; one thread per (b,d); out = bf16(r*wkv).
// ---------------------------------------------------------------------------
__global__ __launch_bounds__(64) void wkv_k(
    const float* __restrict__ kbuf, const float* __restrict__ vbuf,
    const float* __restrict__ rbuf, bf16* __restrict__ outbuf,
    const float* __restrict__ decay, const float* __restrict__ first)
{
    int idx = blockIdx.x * 64 + threadIdx.x;
    int d = idx & 511;
    int b = idx >> 9;
    float w = -__expf(decay[d]);
    float u = first[d];
    float aa = 0.f, bb = 0.f, pp = -1e38f;
    size_t base = (size_t)b * 1024 * 512 + d;
    float kt = kbuf[base], vt = vbuf[base], rt = rbuf[base];
    for (int t = 0; t < 1024; t++) {
        size_t o = base + (size_t)t * 512;
        float kn = 0.f, vn = 0.f, rn = 0.f;
        if (t < 1023) {
            size_t o1 = o + 512;
            kn = kbuf[o1]; vn = vbuf[o1]; rn = rbuf[o1];
        }
        float ww = u + kt;
        float p = pp > ww ? pp : ww;
        float e1 = __expf(pp - p), e2 = __expf(ww - p);
        float out = (e1 * aa + e2 * vt) / (e1 * bb + e2);
        outbuf[o] = __float2bfloat16(rt * out);
        float ww2 = pp + w;
        float p2 = ww2 > kt ? ww2 : kt;
        e1 = __expf(ww2 - p2);
        e2 = __expf(kt - p2);
        aa = e1 * aa + e2 * vt;
        bb = e1 * bb + e2;
        pp = p2;
        kt = kn; vt = vn; rt = rn;
    }
}

__global__ void olens_k(const int* __restrict__ x_len, float* __restrict__ out)
{
    int i = threadIdx.x;
    if (i < 8) {
        int l1 = (x_len[i] - 1) / 2 + 1;
        int ol = (l1 - 1) / 2 + 1;
        out[i] = (float)ol;
    }
}

// ---------------------------------------------------------------------------
extern "C" void kernel_launch(void* const* d_in, const int* in_sizes, int n_in,
                              void* d_out, int out_size, void* d_ws, size_t ws_size,
                              hipStream_t stream)
{
    (void)in_sizes; (void)n_in; (void)out_size; (void)ws_size;
    const float* x         = (const float*)d_in[0];
    const int*   x_len     = (const int*)d_in[1];
    const float* conv1_w   = (const float*)d_in[2];
    const float* conv1_b   = (const float*)d_in[3];
    const float* conv2_w   = (const float*)d_in[4];
    const float* conv2_b   = (const float*)d_in[5];
    const float* conv3_w   = (const float*)d_in[6];
    const float* conv3_b   = (const float*)d_in[7];
    const float* embed_w   = (const float*)d_in[8];
    const float* embed_b   = (const float*)d_in[9];
    const float* embed_ln_g= (const float*)d_in[10];
    const float* embed_ln_b= (const float*)d_in[11];
    const float* ln_att_g  = (const float*)d_in[12];
    const float* ln_att_b  = (const float*)d_in[13];
    const float* att_decay = (const float*)d_in[14];
    const float* att_first = (const float*)d_in[15];
    const float* att_mix_k = (const float*)d_in[16];
    const float* att_mix_v = (const float*)d_in[17];
    const float* att_mix_r = (const float*)d_in[18];
    const float* att_wk    = (const float*)d_in[19];
    const float* att_wv    = (const float*)d_in[20];
    const float* att_wr    = (const float*)d_in[21];
    const float* att_wo    = (const float*)d_in[22];
    const float* ln_ffn_g  = (const float*)d_in[23];
    const float* ln_ffn_b  = (const float*)d_in[24];
    const float* ffn_mix_k = (const float*)d_in[25];
    const float* ffn_mix_r = (const float*)d_in[26];
    const float* ffn_wk    = (const float*)d_in[27];
    const float* ffn_wv    = (const float*)d_in[28];
    const float* ffn_wr    = (const float*)d_in[29];
    const float* final_ln_g= (const float*)d_in[30];
    const float* final_ln_b= (const float*)d_in[31];

    // ---- workspace layout (MiB offsets, ~182 MiB) ----
    // 0..16 h | 16..32 xn | 32..40 rwkvb | 40..64 xkvr (xf aliases 40..56)
    // 64..112 kvrb (k/v/r) | 112..144 kkb
    // conv overlay: c1b 40..80 | c2b(halo) 80..104 | c3b 104..144
    // weights: attT 144..150 | ffnT 150..160 | ffnTv 160..168 | embT 168..178
    //          c2wb 178..179 | c3wb 179..182
    char* wsb = (char*)d_ws;
    float* h     = (float*)(wsb);
    float* xn    = (float*)(wsb + (16LL << 20));
    bf16*  rwkvb = (bf16*) (wsb + (32LL << 20));
    bf16*  xkvr  = (bf16*) (wsb + (40LL << 20));   // [3][8192][512] bf16
    bf16*  xf    = xkvr;                           // [2][8192][512] bf16 (ffn)
    float* kvrb  = (float*)(wsb + (64LL << 20));   // [3][8192][512] f32
    bf16*  kkb   = (bf16*) (wsb + (112LL << 20));  // [8192][2048] bf16
    bf16*  c1b   = (bf16*) (wsb + (40LL << 20));   // (2,2048,40,128)
    bf16*  c2b   = (bf16*) (wsb + (80LL << 20));   // (2,1026,22,256) halo
    bf16*  c3b   = (bf16*) (wsb + (104LL << 20));  // (2048,10240)
    bf16*  attT  = (bf16*) (wsb + (144LL << 20));  // 4 x [1536][512]
    bf16*  ffnT  = (bf16*) (wsb + (150LL << 20));  // 4 x [2560][512]
    bf16*  ffnTv = (bf16*) (wsb + (160LL << 20));  // 4 x [512][2048]
    bf16*  embT  = (bf16*) (wsb + (168LL << 20));  // [512][10240]
    bf16*  c2wb  = (bf16*) (wsb + (178LL << 20));  // 256 x 1152
    bf16*  c3wb  = (bf16*) (wsb + (179LL << 20));  // 512 x 2304

    const size_t MD = 8192LL * 512;

    // ---- weight prep: packed transposed bf16
    transpose_k<<<dim3(16, 16, 4), 256, 0, stream>>>(att_wk, attT, 512, 512, 786432);
    transpose_k<<<dim3(16, 16, 4), 256, 0, stream>>>(att_wv, attT + 262144, 512, 512, 786432);
    transpose_k<<<dim3(16, 16, 4), 256, 0, stream>>>(att_wr, attT + 524288, 512, 512, 786432);
    transpose_k<<<dim3(16, 16, 4), 256, 0, stream>>>(att_wo, attT + 786432LL * 4, 512, 512, 262144);
    transpose_k<<<dim3(64, 16, 4), 256, 0, stream>>>(ffn_wk, ffnT, 512, 2048, 1310720);
    transpose_k<<<dim3(16, 16, 4), 256, 0, stream>>>(ffn_wr, ffnT + 1048576, 512, 512, 1310720);
    transpose_k<<<dim3(16, 64, 4), 256, 0, stream>>>(ffn_wv, ffnTv, 2048, 512, 1048576);
    transpose_k<<<dim3(16, 320, 1), 256, 0, stream>>>(embed_w, embT, 10240, 512, 0);
    reorder_w_k<<<1152, 256, 0, stream>>>(conv2_w, c2wb, 256, 128);
    reorder_w_k<<<4608, 256, 0, stream>>>(conv3_w, c3wb, 512, 256);
    hipMemsetAsync(xn, 0, 16LL << 20, stream);
    hipMemsetAsync(c2b, 0, 2LL * 1026 * 22 * 256 * 2, stream);
    bf16* attToP = attT + 786432LL * 4;  // 4 x [512][512] wo pack

    // ---- conv frontend + embed (split-K x4, atomic), 2 batches per chunk
    for (int chunk = 0; chunk < 4; chunk++) {
        int b0 = chunk * 2;
        conv1_k<<<640, 256, 0, stream>>>(x + (size_t)b0 * 327680, conv1_w, conv1_b, c1b);
        gemm_k<128, B_CONV, EP_CONV_CL, 0, 2048, 40, 2, 128, 0><<<dim3(320, 2), 256, 0, stream>>>(
            c2wb, nullptr, c1b, nullptr, c2b, conv2_b, nullptr, 256, 40960, 1152, 1152);
        gemm_k<128, B_CONV, EP_CONV_T, 0, 1024, 20, 1, 256, 1><<<dim3(320, 4), 256, 0, stream>>>(
            c3wb, nullptr, c2b, nullptr, c3b, conv3_b, nullptr, 512, 40960, 2304, 2304);
        gemm_k<64, B_T, EP_ATOMIC, 0, 0, 0, 0, 0, 0><<<dim3(4, 32, 4), 256, 0, stream>>>(
            c3b, embT, nullptr, xn + (size_t)b0 * 1024 * 512, nullptr, embed_b, nullptr,
            2048, 512, 10240, 2560);
    }
    ln_k<<<2048, 256, 0, stream>>>(xn, h, embed_ln_g, embed_ln_b, 8192);

    // ---- 4 RWKV blocks
    for (int i = 0; i < 4; i++) {
        // time mixing
        ln_k<<<2048, 256, 0, stream>>>(h, xn, ln_att_g + i * 512, ln_att_b + i * 512, 8192);
        mix3_k<<<4096, 256, 0, stream>>>(xn, att_mix_k + i * 512, att_mix_v + i * 512,
                                         att_mix_r + i * 512, xkvr, xkvr + MD, xkvr + 2 * MD);
        gemm_k<64, B_T, EP_KVR, 9, 0, 0, 0, 0, 0><<<dim3(12, 128), 256, 0, stream>>>(
            xkvr, attT + (size_t)i * 786432, nullptr, kvrb, nullptr, nullptr, nullptr,
            8192, 1536, 512, 512);
        wkv_k<<<64, 64, 0, stream>>>(kvrb, kvrb + MD, kvrb + 2 * MD, rwkvb,
                                     att_decay + i * 512, att_first + i * 512);
        gemm_k<64, B_T, EP_ADD, 0, 0, 0, 0, 0, 0><<<dim3(4, 128), 256, 0, stream>>>(
            rwkvb, attToP + (size_t)i * 262144, nullptr, h, nullptr, nullptr, nullptr,
            8192, 512, 512, 512);
        // channel mixing
        ln_k<<<2048, 256, 0, stream>>>(h, xn, ln_ffn_g + i * 512, ln_ffn_b + i * 512, 8192);
        mix2_k<<<4096, 256, 0, stream>>>(xn, ffn_mix_k + i * 512, ffn_mix_r + i * 512,
                                         xf, xf + MD);
        gemm_k<64, B_T, EP_FFN, 11, 0, 0, 0, 0, 0><<<dim3(20, 128), 256, 0, stream>>>(
            xf, ffnT + (size_t)i * 1310720, nullptr, kvrb + 2 * MD, kkb, nullptr, nullptr,
            8192, 2560, 512, 512);
        gemm_k<64, B_T, EP_ADDMUL, 0, 0, 0, 0, 0, 0><<<dim3(4, 128), 256, 0, stream>>>(
            kkb, ffnTv + (size_t)i * 1048576, nullptr, h, nullptr, nullptr, kvrb + 2 * MD,
            8192, 512, 2048, 2048);
    }

    // ---- final LN straight into d_out, then olens
    ln_k<<<2048, 256, 0, stream>>>(h, (float*)d_out, final_ln_g, final_ln_b, 8192);
    olens_k<<<1, 64, 0, stream>>>(x_len, (float*)d_out + 4194304);
}